// Round 10
// baseline (298.044 us; speedup 1.0000x reference)
//
#include <hip/hip_runtime.h>

#define NN 50000
#define NPAD 50048   // rows padded to multiple of 64 for MFMA tiles
#define NE 800000
#define FIN 64
#define H 128
#define NG 16
#define NPART 64         // private pooled-accumulator copies (atomic spreading)
#define NBUCK 196        // buckets of 256 dst nodes
#define BUCK_CAP 4800    // edges per bucket capacity (expected 4096 +- 64)
#define FILLA_BLOCKS 512
#define FILLA_CHUNK 1563  // ceil(NE / FILLA_BLOCKS)
#define ROW_U 64         // uints per node row (128 bf16 feats, 256 B)
#define XROW_U 32        // uints per x row (64 bf16 feats, 128 B)
#define DUMMY NN         // zero pad row used for CSR padding
#define ZERO_I4 32768    // int4s to zero: poolpart = 131072 ints
#define PREP_ITEMS (H * FIN + 2 * H * H + ZERO_I4)
#define PREP_BLOCKS ((PREP_ITEMS + 255) / 256)

typedef __bf16 bf16x8 __attribute__((ext_vector_type(8)));
typedef float f32x4 __attribute__((ext_vector_type(4)));
typedef float f32x2 __attribute__((ext_vector_type(2)));
typedef unsigned int u32x4 __attribute__((ext_vector_type(4)));

// ---- helpers ----
__device__ inline unsigned short bf16r(float x) {
    unsigned int u = __float_as_uint(x);
    return (unsigned short)((u + 0x7fffu + ((u >> 16) & 1u)) >> 16);
}
__device__ inline unsigned int pack_bf16x2(float a, float b) {
    return (unsigned int)bf16r(a) | ((unsigned int)bf16r(b) << 16);
}
__device__ inline float bf_lo(unsigned int u) { return __uint_as_float(u << 16); }
__device__ inline float bf_hi(unsigned int u) { return __uint_as_float(u & 0xffff0000u); }

// packed fp32 add: acc(pair) += {lo(u), hi(u)}
__device__ inline void pkadd(f32x2& a, unsigned int u) {
    f32x2 p;
    p.x = bf_lo(u);
    p.y = bf_hi(u);
    asm("v_pk_add_f32 %0, %1, %0" : "+v"(a) : "v"(p));
}
__device__ inline void bfly(f32x2& a, int m) {
    a.x += __shfl_xor(a.x, m);
    a.y += __shfl_xor(a.y, m);
}

// ====== fillA + prep merged: blocks [0,512) bucket edges; rest convert W + zero pool ======
__global__ __launch_bounds__(256) void fillA_prep_kernel(const int* __restrict__ ei,
                                                         int* __restrict__ gcount,
                                                         unsigned int* __restrict__ ebuf,
                                                         const float* __restrict__ W1,
                                                         const float* __restrict__ W2,
                                                         const float* __restrict__ W3,
                                                         unsigned short* __restrict__ Wt1,
                                                         unsigned short* __restrict__ Wt2,
                                                         unsigned short* __restrict__ Wt3,
                                                         int4* __restrict__ zbuf) {
    const int t = threadIdx.x;
    if (blockIdx.x >= FILLA_BLOCKS) {
        // ---- prep part ----
        int e = (blockIdx.x - FILLA_BLOCKS) * 256 + t;
        if (e < H * FIN) {
            int n = e / FIN, k = e % FIN;
            Wt1[e] = bf16r(W1[k * H + n]);
            return;
        }
        int u = e - H * FIN;
        if (u < 2 * H * H) {
            const float* W = W2;
            unsigned short* Wt = Wt2;
            if (u >= H * H) { W = W3; Wt = Wt3; u -= H * H; }
            int n = u / H, k = u % H;
            Wt[u] = bf16r(W[k * H + n]);
            return;
        }
        int z = u - 2 * H * H;
        if (z < ZERO_I4) zbuf[z] = make_int4(0, 0, 0, 0);  // zero pool partials
        return;
    }
    // ---- fillA part: histogram into 196 buckets of 256 nodes ----
    __shared__ int hist[256];
    __shared__ int base[256];
    hist[t] = 0;
    __syncthreads();
    const int e0 = blockIdx.x * FILLA_CHUNK;
    const int e1 = min(e0 + FILLA_CHUNK, NE);
    for (int e = e0 + t; e < e1; e += 256)
        atomicAdd(&hist[ei[NE + e] >> 8], 1);
    __syncthreads();
    {
        int h = hist[t];
        base[t] = h ? atomicAdd(&gcount[t], h) : 0;
    }
    __syncthreads();
    for (int e = e0 + t; e < e1; e += 256) {
        int d = ei[NE + e];
        int s = ei[e];
        int b = d >> 8;
        int pos = atomicAdd(&base[b], 1);
        ebuf[b * BUCK_CAP + pos] = (unsigned int)s | ((unsigned int)d << 16);
    }
}

// fillB (fused hist+scan+scatter), 196 blocks, 1 node per thread.
// Also: per-graph node counts (pcnt) and fused xprep (xb = bf16(x*dinv)).
__global__ __launch_bounds__(256) void fillB_kernel(const unsigned int* __restrict__ ebuf,
                                                    const int* __restrict__ gcount,
                                                    int* __restrict__ galloc,
                                                    int* __restrict__ pcnt,
                                                    const int* __restrict__ batch,
                                                    const float* __restrict__ x,
                                                    int2* __restrict__ rowse,
                                                    float* __restrict__ dinv,
                                                    unsigned short* __restrict__ xb,
                                                    unsigned short* __restrict__ csr) {
    __shared__ int lh[256];
    __shared__ int lsum[256];
    __shared__ int lcur[256];
    __shared__ int lgc[16];
    __shared__ int base_s;
    const int b = blockIdx.x, t = threadIdx.x;
    const int n0 = b * 256;
    lh[t] = 0;
    if (t < 16) lgc[t] = 0;
    __syncthreads();
    const int ne = gcount[b];
    const unsigned int* __restrict__ eb = ebuf + b * BUCK_CAP;
    for (int i = t; i < ne; i += 256)
        atomicAdd(&lh[(int)(eb[i] >> 16) - n0], 1);
    __syncthreads();
    const int c = lh[t];
    const int p = (c + 7) & ~7;
    const int n = n0 + t;
    if (n < NN) atomicAdd(&lgc[batch[n]], 1);
    lsum[t] = p;
    __syncthreads();
    if (t < 16 && lgc[t]) atomicAdd(&pcnt[t], lgc[t]);
    for (int off = 1; off < 256; off <<= 1) {
        int u = (t >= off) ? lsum[t - off] : 0;
        __syncthreads();
        lsum[t] += u;
        __syncthreads();
    }
    if (t == 255) base_s = atomicAdd(galloc, lsum[255]);
    const int excl = t ? lsum[t - 1] : 0;
    __syncthreads();
    const int st = base_s + excl;
    if (n < NN) {
        rowse[n] = make_int2(st, st + p);
        dinv[n] = rsqrtf((float)c + 1.0f);  // +1 self-loop
    } else if (n < NPAD) {
        rowse[n] = make_int2(0, 0);
        dinv[n] = 0.0f;
    }
    lcur[t] = st;
    __syncthreads();
    for (int i = t; i < ne; i += 256) {
        unsigned int u = eb[i];
        int pos = atomicAdd(&lcur[(int)(u >> 16) - n0], 1);
        csr[pos] = (unsigned short)(u & 0xFFFFu);
    }
    __syncthreads();
    for (int k = st + c; k < st + p; k++) csr[k] = (unsigned short)DUMMY;
    // ---- fused xprep: this block's 256 rows, xb = bf16(x * dinv); pads zero ----
    for (int i = t; i < 4096; i += 256) {  // 256 rows x 16 float4
        int nl = i >> 4;
        int nn = n0 + nl;
        if (nn >= NPAD) continue;
        uint2 o = make_uint2(0u, 0u);
        if (nn < NN) {
            float4 v = *(const float4*)&x[(size_t)nn * 64 + (i & 15) * 4];
            float d = rsqrtf((float)lh[nl] + 1.0f);
            o.x = pack_bf16x2(v.x * d, v.y * d);
            o.y = pack_bf16x2(v.z * d, v.w * d);
        }
        *(uint2*)&xb[(size_t)nn * 64 + (i & 15) * 4] = o;
    }
}

// ---- gather one node's aggregated row slice (16 B/lane; RU uints per row) ----
template <int RU>
__device__ inline void gather_row(const unsigned int* __restrict__ hwc,
                                  const int2* __restrict__ rowse,
                                  const unsigned short* __restrict__ csr,
                                  int n, int u0,
                                  f32x2& a0, f32x2& a1, f32x2& a2, f32x2& a3) {
    uint4 sv = *(const uint4*)&hwc[(size_t)n * RU + u0];  // self-loop term
    a0.x = bf_lo(sv.x); a0.y = bf_hi(sv.x);
    a1.x = bf_lo(sv.y); a1.y = bf_hi(sv.y);
    a2.x = bf_lo(sv.z); a2.y = bf_hi(sv.z);
    a3.x = bf_lo(sv.w); a3.y = bf_hi(sv.w);
    const int2 se = rowse[n];  // start/end, both multiples of 8
    int i = se.x;
    for (; i + 16 <= se.y; i += 16) {  // unroll x2: 16 gathers outstanding
        u32x4 c0 = __builtin_nontemporal_load((const u32x4*)&csr[i]);
        u32x4 c1 = __builtin_nontemporal_load((const u32x4*)&csr[i + 8]);
        int s0 = c0[0] & 0xFFFF, s1 = c0[0] >> 16;
        int s2 = c0[1] & 0xFFFF, s3 = c0[1] >> 16;
        int s4 = c0[2] & 0xFFFF, s5 = c0[2] >> 16;
        int s6 = c0[3] & 0xFFFF, s7 = c0[3] >> 16;
        int t0 = c1[0] & 0xFFFF, t1 = c1[0] >> 16;
        int t2 = c1[1] & 0xFFFF, t3 = c1[1] >> 16;
        int t4 = c1[2] & 0xFFFF, t5 = c1[2] >> 16;
        int t6 = c1[3] & 0xFFFF, t7 = c1[3] >> 16;
        uint4 v0 = *(const uint4*)&hwc[(size_t)s0 * RU + u0];
        uint4 v1 = *(const uint4*)&hwc[(size_t)s1 * RU + u0];
        uint4 v2 = *(const uint4*)&hwc[(size_t)s2 * RU + u0];
        uint4 v3 = *(const uint4*)&hwc[(size_t)s3 * RU + u0];
        uint4 v4 = *(const uint4*)&hwc[(size_t)s4 * RU + u0];
        uint4 v5 = *(const uint4*)&hwc[(size_t)s5 * RU + u0];
        uint4 v6 = *(const uint4*)&hwc[(size_t)s6 * RU + u0];
        uint4 v7 = *(const uint4*)&hwc[(size_t)s7 * RU + u0];
        uint4 w0 = *(const uint4*)&hwc[(size_t)t0 * RU + u0];
        uint4 w1 = *(const uint4*)&hwc[(size_t)t1 * RU + u0];
        uint4 w2 = *(const uint4*)&hwc[(size_t)t2 * RU + u0];
        uint4 w3 = *(const uint4*)&hwc[(size_t)t3 * RU + u0];
        uint4 w4 = *(const uint4*)&hwc[(size_t)t4 * RU + u0];
        uint4 w5 = *(const uint4*)&hwc[(size_t)t5 * RU + u0];
        uint4 w6 = *(const uint4*)&hwc[(size_t)t6 * RU + u0];
        uint4 w7 = *(const uint4*)&hwc[(size_t)t7 * RU + u0];
        pkadd(a0, v0.x); pkadd(a1, v0.y); pkadd(a2, v0.z); pkadd(a3, v0.w);
        pkadd(a0, v1.x); pkadd(a1, v1.y); pkadd(a2, v1.z); pkadd(a3, v1.w);
        pkadd(a0, v2.x); pkadd(a1, v2.y); pkadd(a2, v2.z); pkadd(a3, v2.w);
        pkadd(a0, v3.x); pkadd(a1, v3.y); pkadd(a2, v3.z); pkadd(a3, v3.w);
        pkadd(a0, v4.x); pkadd(a1, v4.y); pkadd(a2, v4.z); pkadd(a3, v4.w);
        pkadd(a0, v5.x); pkadd(a1, v5.y); pkadd(a2, v5.z); pkadd(a3, v5.w);
        pkadd(a0, v6.x); pkadd(a1, v6.y); pkadd(a2, v6.z); pkadd(a3, v6.w);
        pkadd(a0, v7.x); pkadd(a1, v7.y); pkadd(a2, v7.z); pkadd(a3, v7.w);
        pkadd(a0, w0.x); pkadd(a1, w0.y); pkadd(a2, w0.z); pkadd(a3, w0.w);
        pkadd(a0, w1.x); pkadd(a1, w1.y); pkadd(a2, w1.z); pkadd(a3, w1.w);
        pkadd(a0, w2.x); pkadd(a1, w2.y); pkadd(a2, w2.z); pkadd(a3, w2.w);
        pkadd(a0, w3.x); pkadd(a1, w3.y); pkadd(a2, w3.z); pkadd(a3, w3.w);
        pkadd(a0, w4.x); pkadd(a1, w4.y); pkadd(a2, w4.z); pkadd(a3, w4.w);
        pkadd(a0, w5.x); pkadd(a1, w5.y); pkadd(a2, w5.z); pkadd(a3, w5.w);
        pkadd(a0, w6.x); pkadd(a1, w6.y); pkadd(a2, w6.z); pkadd(a3, w6.w);
        pkadd(a0, w7.x); pkadd(a1, w7.y); pkadd(a2, w7.z); pkadd(a3, w7.w);
    }
    if (i < se.y) {  // remainder is exactly one 8-group
        u32x4 c = __builtin_nontemporal_load((const u32x4*)&csr[i]);
        int s0 = c[0] & 0xFFFF, s1 = c[0] >> 16;
        int s2 = c[1] & 0xFFFF, s3 = c[1] >> 16;
        int s4 = c[2] & 0xFFFF, s5 = c[2] >> 16;
        int s6 = c[3] & 0xFFFF, s7 = c[3] >> 16;
        uint4 v0 = *(const uint4*)&hwc[(size_t)s0 * RU + u0];
        uint4 v1 = *(const uint4*)&hwc[(size_t)s1 * RU + u0];
        uint4 v2 = *(const uint4*)&hwc[(size_t)s2 * RU + u0];
        uint4 v3 = *(const uint4*)&hwc[(size_t)s3 * RU + u0];
        uint4 v4 = *(const uint4*)&hwc[(size_t)s4 * RU + u0];
        uint4 v5 = *(const uint4*)&hwc[(size_t)s5 * RU + u0];
        uint4 v6 = *(const uint4*)&hwc[(size_t)s6 * RU + u0];
        uint4 v7 = *(const uint4*)&hwc[(size_t)s7 * RU + u0];
        pkadd(a0, v0.x); pkadd(a1, v0.y); pkadd(a2, v0.z); pkadd(a3, v0.w);
        pkadd(a0, v1.x); pkadd(a1, v1.y); pkadd(a2, v1.z); pkadd(a3, v1.w);
        pkadd(a0, v2.x); pkadd(a1, v2.y); pkadd(a2, v2.z); pkadd(a3, v2.w);
        pkadd(a0, v3.x); pkadd(a1, v3.y); pkadd(a2, v3.z); pkadd(a3, v3.w);
        pkadd(a0, v4.x); pkadd(a1, v4.y); pkadd(a2, v4.z); pkadd(a3, v4.w);
        pkadd(a0, v5.x); pkadd(a1, v5.y); pkadd(a2, v5.z); pkadd(a3, v5.w);
        pkadd(a0, v6.x); pkadd(a1, v6.y); pkadd(a2, v6.z); pkadd(a3, v6.w);
        pkadd(a0, v7.x); pkadd(a1, v7.y); pkadd(a2, v7.z); pkadd(a3, v7.w);
    }
}

#define LSTRIDE 130

// ===== gemm1 fused: per-block gather of x-hat (64-dim) -> LDS -> MFMA W1, relu+b1 =====
__global__ __launch_bounds__(256) void gemm1f_kernel(const unsigned short* __restrict__ xb,
                                                     const int2* __restrict__ rowse,
                                                     const unsigned short* __restrict__ csr,
                                                     const float* __restrict__ dinv,
                                                     const unsigned short* __restrict__ Wt,
                                                     const float* __restrict__ bias,
                                                     unsigned int* __restrict__ outu) {
    __shared__ unsigned int als[64 * 36];  // 64 rows x 32 uints, +4 pad (bank-safe)
    __shared__ float ls[64 * LSTRIDE];
    const int wave = threadIdx.x >> 6, lane = threadIdx.x & 63;
    const int m15 = lane & 15, quad = lane >> 4;
    const int row0 = blockIdx.x * 64;

    {  // gather phase: 8 lanes/node, 32 nodes/pass, 2 passes
        const int u0 = (threadIdx.x & 7) * 4;
#pragma unroll
        for (int p = 0; p < 2; p++) {
            const int nl = p * 32 + (threadIdx.x >> 3);
            const int n = row0 + nl;
            f32x2 a0, a1, a2, a3;
            gather_row<XROW_U>((const unsigned int*)xb, rowse, csr, n, u0, a0, a1, a2, a3);
            const float d = dinv[n];
            u32x4 o;
            o[0] = pack_bf16x2(a0.x * d, a0.y * d);
            o[1] = pack_bf16x2(a1.x * d, a1.y * d);
            o[2] = pack_bf16x2(a2.x * d, a2.y * d);
            o[3] = pack_bf16x2(a3.x * d, a3.y * d);
            *(u32x4*)&als[nl * 36 + (threadIdx.x & 7) * 4] = o;
        }
    }
    __syncthreads();

    bf16x8 a[2];
#pragma unroll
    for (int ks = 0; ks < 2; ks++)
        a[ks] = *(const bf16x8*)&als[(wave * 16 + m15) * 36 + ks * 16 + quad * 4];

    const int lrow = wave * 16 + quad * 4;
#pragma unroll
    for (int ct = 0; ct < 8; ct++) {
        f32x4 acc = {0.f, 0.f, 0.f, 0.f};
#pragma unroll
        for (int ks = 0; ks < 2; ks++) {
            bf16x8 bfr = *(const bf16x8*)&Wt[(ct * 16 + m15) * FIN + ks * 32 + quad * 8];
            acc = __builtin_amdgcn_mfma_f32_16x16x32_bf16(a[ks], bfr, acc, 0, 0, 0);
        }
        float bv = bias[ct * 16 + m15];
#pragma unroll
        for (int r = 0; r < 4; r++)
            ls[(lrow + r) * LSTRIDE + ct * 16 + m15] = fmaxf(acc[r] + bv, 0.f);
    }
    __syncthreads();

#pragma unroll
    for (int k = 0; k < 4; k++) {
        int idx = threadIdx.x + 256 * k;
        int row = idx >> 4, q = idx & 15;
        const float* p = &ls[row * LSTRIDE + q * 8];
        u32x4 o;
        o[0] = pack_bf16x2(p[0], p[1]);
        o[1] = pack_bf16x2(p[2], p[3]);
        o[2] = pack_bf16x2(p[4], p[5]);
        o[3] = pack_bf16x2(p[6], p[7]);
        if (row0 + row >= NN) { o[0] = o[1] = o[2] = o[3] = 0u; }
        __builtin_nontemporal_store(
            o, (u32x4*)&outu[(size_t)(row0 + row) * ROW_U + q * 4]);
    }
}

// ===== gemm2: plain row-major MFMA, epilogue *dinv (pre-scale for gather) =====
__global__ __launch_bounds__(256) void gemm2_kernel(const unsigned short* __restrict__ hb,
                                                    const unsigned short* __restrict__ Wt,
                                                    const float* __restrict__ dinv,
                                                    unsigned int* __restrict__ outu) {
    __shared__ float ls[64 * LSTRIDE];
    const int wave = threadIdx.x >> 6, lane = threadIdx.x & 63;
    const int m15 = lane & 15, quad = lane >> 4;
    const int row0 = blockIdx.x * 64;
    const int arow = row0 + wave * 16 + m15;

    bf16x8 a[4];
#pragma unroll
    for (int ks = 0; ks < 4; ks++)
        a[ks] = *(const bf16x8*)&hb[(size_t)arow * H + ks * 32 + quad * 8];

    const int lrow = wave * 16 + quad * 4;
    float dv[4];
#pragma unroll
    for (int r = 0; r < 4; r++) dv[r] = dinv[row0 + lrow + r];

#pragma unroll
    for (int ct = 0; ct < 8; ct++) {
        f32x4 acc = {0.f, 0.f, 0.f, 0.f};
#pragma unroll
        for (int ks = 0; ks < 4; ks++) {
            bf16x8 bfr = *(const bf16x8*)&Wt[(ct * 16 + m15) * H + ks * 32 + quad * 8];
            acc = __builtin_amdgcn_mfma_f32_16x16x32_bf16(a[ks], bfr, acc, 0, 0, 0);
        }
#pragma unroll
        for (int r = 0; r < 4; r++)
            ls[(lrow + r) * LSTRIDE + ct * 16 + m15] = acc[r] * dv[r];
    }
    __syncthreads();

#pragma unroll
    for (int k = 0; k < 4; k++) {
        int idx = threadIdx.x + 256 * k;
        int row = idx >> 4, q = idx & 15;
        const float* p = &ls[row * LSTRIDE + q * 8];
        u32x4 o;
        o[0] = pack_bf16x2(p[0], p[1]);
        o[1] = pack_bf16x2(p[2], p[3]);
        o[2] = pack_bf16x2(p[4], p[5]);
        o[3] = pack_bf16x2(p[6], p[7]);
        __builtin_nontemporal_store(
            o, (u32x4*)&outu[(size_t)(row0 + row) * ROW_U + q * 4]);
    }
}

// ===== gemm3 fused: gather H2=relu(agg(hwb)*d+b2) -> LDS -> MFMA W3, epi *dinv =====
// H2 never hits global memory.
__global__ __launch_bounds__(256) void gemm3f_kernel(const unsigned int* __restrict__ hwc,
                                                     const int2* __restrict__ rowse,
                                                     const unsigned short* __restrict__ csr,
                                                     const float* __restrict__ dinv,
                                                     const float* __restrict__ bias,
                                                     const unsigned short* __restrict__ Wt,
                                                     unsigned int* __restrict__ outu) {
    __shared__ unsigned int als[64 * 68];  // 64 rows x 64 uints, +4 pad (bank-safe)
    __shared__ float ls[64 * LSTRIDE];
    const int wave = threadIdx.x >> 6, lane = threadIdx.x & 63;
    const int m15 = lane & 15, quad = lane >> 4;
    const int row0 = blockIdx.x * 64;

    {  // gather phase: 16 lanes/node, 16 nodes/pass, 4 passes
        const int u = threadIdx.x & 15;
        const int u0 = u * 4;
        const float2* bp = (const float2*)bias + u0;
        float2 q0 = bp[0], q1 = bp[1], q2 = bp[2], q3 = bp[3];
#pragma unroll
        for (int p = 0; p < 4; p++) {
            const int nl = p * 16 + (threadIdx.x >> 4);
            const int n = row0 + nl;
            f32x2 a0, a1, a2, a3;
            gather_row<ROW_U>(hwc, rowse, csr, n, u0, a0, a1, a2, a3);
            const float d = dinv[n];
            u32x4 o;
            o[0] = pack_bf16x2(fmaxf(a0.x * d + q0.x, 0.f), fmaxf(a0.y * d + q0.y, 0.f));
            o[1] = pack_bf16x2(fmaxf(a1.x * d + q1.x, 0.f), fmaxf(a1.y * d + q1.y, 0.f));
            o[2] = pack_bf16x2(fmaxf(a2.x * d + q2.x, 0.f), fmaxf(a2.y * d + q2.y, 0.f));
            o[3] = pack_bf16x2(fmaxf(a3.x * d + q3.x, 0.f), fmaxf(a3.y * d + q3.y, 0.f));
            *(u32x4*)&als[nl * 68 + u0] = o;
        }
    }
    __syncthreads();

    bf16x8 a[4];
#pragma unroll
    for (int ks = 0; ks < 4; ks++)
        a[ks] = *(const bf16x8*)&als[(wave * 16 + m15) * 68 + ks * 16 + quad * 4];

    const int lrow = wave * 16 + quad * 4;
    float dv[4];
#pragma unroll
    for (int r = 0; r < 4; r++) dv[r] = dinv[row0 + lrow + r];

#pragma unroll
    for (int ct = 0; ct < 8; ct++) {
        f32x4 acc = {0.f, 0.f, 0.f, 0.f};
#pragma unroll
        for (int ks = 0; ks < 4; ks++) {
            bf16x8 bfr = *(const bf16x8*)&Wt[(ct * 16 + m15) * H + ks * 32 + quad * 8];
            acc = __builtin_amdgcn_mfma_f32_16x16x32_bf16(a[ks], bfr, acc, 0, 0, 0);
        }
#pragma unroll
        for (int r = 0; r < 4; r++)
            ls[(lrow + r) * LSTRIDE + ct * 16 + m15] = acc[r] * dv[r];
    }
    __syncthreads();

#pragma unroll
    for (int k = 0; k < 4; k++) {
        int idx = threadIdx.x + 256 * k;
        int row = idx >> 4, q = idx & 15;
        const float* p = &ls[row * LSTRIDE + q * 8];
        u32x4 o;
        o[0] = pack_bf16x2(p[0], p[1]);
        o[1] = pack_bf16x2(p[2], p[3]);
        o[2] = pack_bf16x2(p[4], p[5]);
        o[3] = pack_bf16x2(p[6], p[7]);
        __builtin_nontemporal_store(
            o, (u32x4*)&outu[(size_t)(row0 + row) * ROW_U + q * 4]);
    }
}

// ====== full-row gather aggregation (128-dim): 16 lanes/node ======
// MODE 2: relu(a*d + bias)*d -> bf16 (agg3, pre-scaled for layer-4 gather).
// MODE 1: pooled (layer 4, no gemm): gather, *d, pool atomics.
template <int MODE>
__global__ __launch_bounds__(256) void agg_kernel(const unsigned int* __restrict__ hwc,
                                                  const int2* __restrict__ rowse,
                                                  const unsigned short* __restrict__ csr,
                                                  const float* __restrict__ dinv,
                                                  const float* __restrict__ bias,
                                                  const int* __restrict__ batch,
                                                  float* __restrict__ poolpart,
                                                  unsigned int* __restrict__ outc) {
    const int u = threadIdx.x & 15;
    const int u0 = u * 4;
    if (MODE != 1) {
        const int n = blockIdx.x * 16 + (threadIdx.x >> 4);
        f32x2 a0, a1, a2, a3;
        gather_row<ROW_U>(hwc, rowse, csr, n, u0, a0, a1, a2, a3);
        const float d = dinv[n];
        const float2* bp = (const float2*)bias + u0;
        float2 q0 = bp[0], q1 = bp[1], q2 = bp[2], q3 = bp[3];
        float r0 = fmaxf(a0.x * d + q0.x, 0.f), r1 = fmaxf(a0.y * d + q0.y, 0.f);
        float r2 = fmaxf(a1.x * d + q1.x, 0.f), r3 = fmaxf(a1.y * d + q1.y, 0.f);
        float r4 = fmaxf(a2.x * d + q2.x, 0.f), r5 = fmaxf(a2.y * d + q2.y, 0.f);
        float r6 = fmaxf(a3.x * d + q3.x, 0.f), r7 = fmaxf(a3.y * d + q3.y, 0.f);
        if (MODE == 2) {  // pre-scale for the gemm-free layer-4 gather
            r0 *= d; r1 *= d; r2 *= d; r3 *= d;
            r4 *= d; r5 *= d; r6 *= d; r7 *= d;
        }
        u32x4 o;
        o[0] = pack_bf16x2(r0, r1);
        o[1] = pack_bf16x2(r2, r3);
        o[2] = pack_bf16x2(r4, r5);
        o[3] = pack_bf16x2(r6, r7);
        __builtin_nontemporal_store(o, (u32x4*)&outc[(size_t)n * ROW_U + u0]);
        return;
    }
    // ---- MODE 1: layer-4 aggregation + pooling ----
    __shared__ float lds[4][128];
    const int nip = threadIdx.x >> 4;  // node-in-pass 0..15
    const int lane = threadIdx.x & 63, wave = threadIdx.x >> 6;
    const int n0 = blockIdx.x * 64;
    const int copy = blockIdx.x & (NPART - 1);
    const int gfirst0 = batch[n0];
    const bool blockUni = (gfirst0 == batch[min(n0 + 63, NN - 1)]);
    float* __restrict__ ppb = poolpart + copy * (NG * H);
    f32x2 acc0 = {0.f, 0.f}, acc1 = {0.f, 0.f}, acc2 = {0.f, 0.f}, acc3 = {0.f, 0.f};
#pragma unroll
    for (int p = 0; p < 4; p++) {
        const int n = n0 + p * 16 + nip;
        f32x2 t0, t1, t2, t3;
        gather_row<ROW_U>(hwc, rowse, csr, n, u0, t0, t1, t2, t3);
        const float d = dinv[n];  // 0 for pad rows -> they vanish
        t0 *= d; t1 *= d; t2 *= d; t3 *= d;
        if (blockUni) {
            acc0 += t0; acc1 += t1; acc2 += t2; acc3 += t3;
        } else {  // rare graph-boundary block (<=15 of 782)
            const int gb = batch[min(n, NN - 1)];
            const bool uni = (__shfl(gb, 0) == __shfl(gb, 63));
            if (uni) {
                bfly(t0, 16); bfly(t1, 16); bfly(t2, 16); bfly(t3, 16);
                bfly(t0, 32); bfly(t1, 32); bfly(t2, 32); bfly(t3, 32);
                if (lane < 16) {
                    float* q = ppb + __shfl(gb, 0) * H + lane * 8;
                    atomicAdd(&q[0], t0.x); atomicAdd(&q[1], t0.y);
                    atomicAdd(&q[2], t1.x); atomicAdd(&q[3], t1.y);
                    atomicAdd(&q[4], t2.x); atomicAdd(&q[5], t2.y);
                    atomicAdd(&q[6], t3.x); atomicAdd(&q[7], t3.y);
                }
            } else if (n < NN) {
                float* q = ppb + gb * H + u * 8;
                atomicAdd(&q[0], t0.x); atomicAdd(&q[1], t0.y);
                atomicAdd(&q[2], t1.x); atomicAdd(&q[3], t1.y);
                atomicAdd(&q[4], t2.x); atomicAdd(&q[5], t2.y);
                atomicAdd(&q[6], t3.x); atomicAdd(&q[7], t3.y);
            }
        }
    }
    if (blockUni) {
        bfly(acc0, 16); bfly(acc1, 16); bfly(acc2, 16); bfly(acc3, 16);
        bfly(acc0, 32); bfly(acc1, 32); bfly(acc2, 32); bfly(acc3, 32);
        if (lane < 16) {
            float* q = &lds[wave][lane * 8];
            q[0] = acc0.x; q[1] = acc0.y;
            q[2] = acc1.x; q[3] = acc1.y;
            q[4] = acc2.x; q[5] = acc2.y;
            q[6] = acc3.x; q[7] = acc3.y;
        }
        __syncthreads();
        if (threadIdx.x < 128) {
            float tot = lds[0][threadIdx.x] + lds[1][threadIdx.x] +
                        lds[2][threadIdx.x] + lds[3][threadIdx.x];
            atomicAdd(&ppb[gfirst0 * H + threadIdx.x], tot);
        }
    }
}

// ===== final MLP: reduce NPART copies -> mean -> @W4+b4 -> @lw1 relu -> @lw2 =====
__global__ __launch_bounds__(1024) void mlp_kernel(const float* __restrict__ poolpart,
                                                   const int* __restrict__ pcnt,
                                                   const float* __restrict__ W4,
                                                   const float* __restrict__ b4,
                                                   const float* __restrict__ lw1,
                                                   const float* __restrict__ lb1,
                                                   const float* __restrict__ lw2,
                                                   const float* __restrict__ lb2,
                                                   float* __restrict__ out) {
    __shared__ float mean_s[NG * H];
    __shared__ float z_s[NG * H];
    __shared__ float cnt_s[NG];
    __shared__ float hid_s[NG * 64];
    int tid = threadIdx.x;
    if (tid < NG) cnt_s[tid] = fmaxf((float)pcnt[tid], 1.0f);
    __syncthreads();
    for (int i = tid; i < NG * H; i += 1024) {
        float s = 0.f;
        for (int p = 0; p < NPART; p++) s += poolpart[p * (NG * H) + i];
        mean_s[i] = s / cnt_s[i >> 7];
    }
    __syncthreads();
#pragma unroll
    for (int r = 0; r < 2; r++) {
        int i = tid + r * 1024;
        int g = i >> 7, j = i & (H - 1);
        float acc = b4[j];
        for (int f = 0; f < H; f++) acc += mean_s[g * H + f] * W4[f * H + j];
        z_s[i] = acc;
    }
    __syncthreads();
    {
        int g = tid >> 6, j = tid & 63;
        float acc = lb1[j];
        for (int f = 0; f < H; f++) acc += z_s[g * H + f] * lw1[f * 64 + j];
        hid_s[g * 64 + j] = fmaxf(acc, 0.f);
    }
    __syncthreads();
    if (tid < 32) {
        int g = tid >> 1, c = tid & 1;
        float acc = lb2[c];
        for (int j = 0; j < 64; j++) acc += hid_s[g * 64 + j] * lw2[j * 2 + c];
        out[g * 2 + c] = acc;
    }
}

extern "C" void kernel_launch(void* const* d_in, const int* in_sizes, int n_in,
                              void* d_out, int out_size, void* d_ws, size_t ws_size,
                              hipStream_t stream) {
    const float* x = (const float*)d_in[0];
    const int* ei = (const int*)d_in[1];
    const int* batch = (const int*)d_in[2];
    const float* W1 = (const float*)d_in[3];
    const float* b1 = (const float*)d_in[4];
    const float* W2 = (const float*)d_in[5];
    const float* b2 = (const float*)d_in[6];
    const float* W3 = (const float*)d_in[7];
    const float* b3 = (const float*)d_in[8];
    const float* W4 = (const float*)d_in[9];
    const float* b4 = (const float*)d_in[10];
    const float* lw1 = (const float*)d_in[11];
    const float* lb1 = (const float*)d_in[12];
    const float* lw2 = (const float*)d_in[13];
    const float* lb2 = (const float*)d_in[14];
    float* out = (float*)d_out;

    // workspace layout (4-byte units; sizes annotated in ints); ~39.5 MB
    int* wsi = (int*)d_ws;
    int* gcount = wsi;                                      // @0        256
    int* galloc = wsi + 256;                                // @256      1
    int* pcnt = wsi + 280;                                  // @280      16 (zeroed to 512)
    float* poolpart = (float*)(wsi + 512);                  // @512      131072 (NPART*NG*H)
    int2* rowse = (int2*)(wsi + 131584);                    // @131584   100096 (NPAD int2)
    unsigned short* csr = (unsigned short*)(wsi + 231680);  // @231680   600000 (1.2M ushorts)
    float* dinv = (float*)(wsi + 831680);                   // @831680   50048
    unsigned short* Wt1 = (unsigned short*)(wsi + 881728);  // @881728   4096 (8192 shorts)
    unsigned short* Wt2 = (unsigned short*)(wsi + 885824);  // @885824   8192 (16384 shorts)
    unsigned short* Wt3 = (unsigned short*)(wsi + 894016);  // @894016   8192
    unsigned short* xb = (unsigned short*)(wsi + 910400);   // @910400   1601536 (NPAD*64 shorts)
    unsigned int* hb = (unsigned int*)(wsi + 2511936);      // @2511936  3203072 (NPAD*64 uints)
    unsigned int* hwb = (unsigned int*)(wsi + 5715008);     // @5715008  3203072
    unsigned int* ebuf = (unsigned int*)(wsi + 8918080);    // @8918080  940800 -> ends 9858880

    const int gemmBlocks = NPAD / 64;          // 782
    const int agg0Blocks = NPAD / 16;          // 3128 (16 nodes/block, 128-dim rows)
    const int poolBlocks = NPAD / 64;          // 782 (64 nodes/block, pooled)

    // ---- zero control vars (tiny); pool partials zeroed inside prep ----
    hipMemsetAsync(wsi, 0, 512 * sizeof(int), stream);
    fillA_prep_kernel<<<FILLA_BLOCKS + PREP_BLOCKS, 256, 0, stream>>>(
        ei, gcount, ebuf, W1, W2, W3, Wt1, Wt2, Wt3, (int4*)poolpart);
    fillB_kernel<<<NBUCK, 256, 0, stream>>>(ebuf, gcount, galloc, pcnt, batch, x,
                                            rowse, dinv, xb, csr);

    // ---- layer 1: fused gather(x-hat) + GEMM W1 + relu/b1 -> hb (H1) ----
    gemm1f_kernel<<<gemmBlocks, 256, 0, stream>>>(xb, rowse, csr, dinv, Wt1, b1, hb);
    // ---- layer 2 GEMM: hwb = (H1 @ W2) * dinv ----
    gemm2_kernel<<<gemmBlocks, 256, 0, stream>>>((unsigned short*)hb, Wt2, dinv, hwb);
    // ---- layer 2 agg + layer 3 GEMM fused: hb = (relu(agg(hwb)*d+b2) @ W3) * dinv ----
    gemm3f_kernel<<<gemmBlocks, 256, 0, stream>>>(hwb, rowse, csr, dinv, b2, Wt3, hb);
    // ---- layer 3 agg (pre-scaled for layer-4): hwb = relu(agg(hb)*d+b3)*d ----
    agg_kernel<2><<<agg0Blocks, 256, 0, stream>>>(hb, rowse, csr, dinv, b3, batch,
                                                  nullptr, hwb);
    // ---- layer 4: aggregation + pooling directly on h3' (W4 folded into MLP) ----
    agg_kernel<1><<<poolBlocks, 256, 0, stream>>>(hwb, rowse, csr, dinv, nullptr, batch,
                                                  poolpart, nullptr);

    // ---- final MLP (applies W4, b4, then the classifier) ----
    mlp_kernel<<<1, 1024, 0, stream>>>(poolpart, pcnt, W4, b4, lw1, lb1, lw2, lb2, out);
}

// Round 11
// 293.670 us; speedup vs baseline: 1.0149x; 1.0149x over previous
//
#include <hip/hip_runtime.h>

#define NN 50000
#define NPAD 50048   // rows padded to multiple of 64 for MFMA tiles
#define NE 800000
#define FIN 64
#define H 128
#define NG 16
#define NPART 64         // private pooled-accumulator copies (atomic spreading)
#define NBUCK 196        // buckets of 256 dst nodes
#define BUCK_CAP 4800    // edges per bucket capacity (expected 4096 +- 64)
#define FILLA_BLOCKS 512
#define FILLA_CHUNK 1563  // ceil(NE / FILLA_BLOCKS)
#define ROW_U 64         // uints per node row (128 bf16 feats, 256 B)
#define XROW_U 32        // uints per x row (64 bf16 feats, 128 B)
#define DUMMY NN         // zero pad row used for CSR padding
#define ZERO_I4 32768    // int4s to zero: poolpart = 131072 ints
#define PREP_ITEMS (H * FIN + 2 * H * H + ZERO_I4)
#define PREP_BLOCKS ((PREP_ITEMS + 255) / 256)

typedef __bf16 bf16x8 __attribute__((ext_vector_type(8)));
typedef float f32x4 __attribute__((ext_vector_type(4)));
typedef float f32x2 __attribute__((ext_vector_type(2)));
typedef unsigned int u32x4 __attribute__((ext_vector_type(4)));

// ---- helpers ----
__device__ inline unsigned short bf16r(float x) {
    unsigned int u = __float_as_uint(x);
    return (unsigned short)((u + 0x7fffu + ((u >> 16) & 1u)) >> 16);
}
__device__ inline unsigned int pack_bf16x2(float a, float b) {
    return (unsigned int)bf16r(a) | ((unsigned int)bf16r(b) << 16);
}
__device__ inline float bf_lo(unsigned int u) { return __uint_as_float(u << 16); }
__device__ inline float bf_hi(unsigned int u) { return __uint_as_float(u & 0xffff0000u); }

// packed fp32 add: acc(pair) += {lo(u), hi(u)}
__device__ inline void pkadd(f32x2& a, unsigned int u) {
    f32x2 p;
    p.x = bf_lo(u);
    p.y = bf_hi(u);
    asm("v_pk_add_f32 %0, %1, %0" : "+v"(a) : "v"(p));
}
__device__ inline void bfly(f32x2& a, int m) {
    a.x += __shfl_xor(a.x, m);
    a.y += __shfl_xor(a.y, m);
}

// ====== fillA + prep merged: blocks [0,512) bucket edges; rest convert W + zero pool ======
__global__ __launch_bounds__(256) void fillA_prep_kernel(const int* __restrict__ ei,
                                                         int* __restrict__ gcount,
                                                         unsigned int* __restrict__ ebuf,
                                                         const float* __restrict__ W1,
                                                         const float* __restrict__ W2,
                                                         const float* __restrict__ W3,
                                                         unsigned short* __restrict__ Wt1,
                                                         unsigned short* __restrict__ Wt2,
                                                         unsigned short* __restrict__ Wt3,
                                                         int4* __restrict__ zbuf) {
    const int t = threadIdx.x;
    if (blockIdx.x >= FILLA_BLOCKS) {
        // ---- prep part ----
        int e = (blockIdx.x - FILLA_BLOCKS) * 256 + t;
        if (e < H * FIN) {
            int n = e / FIN, k = e % FIN;
            Wt1[e] = bf16r(W1[k * H + n]);
            return;
        }
        int u = e - H * FIN;
        if (u < 2 * H * H) {
            const float* W = W2;
            unsigned short* Wt = Wt2;
            if (u >= H * H) { W = W3; Wt = Wt3; u -= H * H; }
            int n = u / H, k = u % H;
            Wt[u] = bf16r(W[k * H + n]);
            return;
        }
        int z = u - 2 * H * H;
        if (z < ZERO_I4) zbuf[z] = make_int4(0, 0, 0, 0);  // zero pool partials
        return;
    }
    // ---- fillA part: histogram into 196 buckets of 256 nodes ----
    __shared__ int hist[256];
    __shared__ int base[256];
    hist[t] = 0;
    __syncthreads();
    const int e0 = blockIdx.x * FILLA_CHUNK;
    const int e1 = min(e0 + FILLA_CHUNK, NE);
    for (int e = e0 + t; e < e1; e += 256)
        atomicAdd(&hist[ei[NE + e] >> 8], 1);
    __syncthreads();
    {
        int h = hist[t];
        base[t] = h ? atomicAdd(&gcount[t], h) : 0;
    }
    __syncthreads();
    for (int e = e0 + t; e < e1; e += 256) {
        int d = ei[NE + e];
        int s = ei[e];
        int b = d >> 8;
        int pos = atomicAdd(&base[b], 1);
        ebuf[b * BUCK_CAP + pos] = (unsigned int)s | ((unsigned int)d << 16);
    }
}

// fillB (fused hist+scan+scatter), 196 blocks, 1 node per thread.
// Also: per-graph node counts (pcnt) and fused xprep (xb = bf16(x*dinv)).
__global__ __launch_bounds__(256) void fillB_kernel(const unsigned int* __restrict__ ebuf,
                                                    const int* __restrict__ gcount,
                                                    int* __restrict__ galloc,
                                                    int* __restrict__ pcnt,
                                                    const int* __restrict__ batch,
                                                    const float* __restrict__ x,
                                                    int2* __restrict__ rowse,
                                                    float* __restrict__ dinv,
                                                    unsigned short* __restrict__ xb,
                                                    unsigned short* __restrict__ csr) {
    __shared__ int lh[256];
    __shared__ int lsum[256];
    __shared__ int lcur[256];
    __shared__ int lgc[16];
    __shared__ int base_s;
    const int b = blockIdx.x, t = threadIdx.x;
    const int n0 = b * 256;
    lh[t] = 0;
    if (t < 16) lgc[t] = 0;
    __syncthreads();
    const int ne = gcount[b];
    const unsigned int* __restrict__ eb = ebuf + b * BUCK_CAP;
    for (int i = t; i < ne; i += 256)
        atomicAdd(&lh[(int)(eb[i] >> 16) - n0], 1);
    __syncthreads();
    const int c = lh[t];
    const int p = (c + 7) & ~7;
    const int n = n0 + t;
    if (n < NN) atomicAdd(&lgc[batch[n]], 1);
    lsum[t] = p;
    __syncthreads();
    if (t < 16 && lgc[t]) atomicAdd(&pcnt[t], lgc[t]);
    for (int off = 1; off < 256; off <<= 1) {
        int u = (t >= off) ? lsum[t - off] : 0;
        __syncthreads();
        lsum[t] += u;
        __syncthreads();
    }
    if (t == 255) base_s = atomicAdd(galloc, lsum[255]);
    const int excl = t ? lsum[t - 1] : 0;
    __syncthreads();
    const int st = base_s + excl;
    if (n < NN) {
        rowse[n] = make_int2(st, st + p);
        dinv[n] = rsqrtf((float)c + 1.0f);  // +1 self-loop
    } else if (n < NPAD) {
        rowse[n] = make_int2(0, 0);
        dinv[n] = 0.0f;
    }
    lcur[t] = st;
    __syncthreads();
    for (int i = t; i < ne; i += 256) {
        unsigned int u = eb[i];
        int pos = atomicAdd(&lcur[(int)(u >> 16) - n0], 1);
        csr[pos] = (unsigned short)(u & 0xFFFFu);
    }
    __syncthreads();
    for (int k = st + c; k < st + p; k++) csr[k] = (unsigned short)DUMMY;
    // ---- fused xprep: this block's 256 rows, xb = bf16(x * dinv); pads zero ----
    for (int i = t; i < 4096; i += 256) {  // 256 rows x 16 float4
        int nl = i >> 4;
        int nn = n0 + nl;
        if (nn >= NPAD) continue;
        uint2 o = make_uint2(0u, 0u);
        if (nn < NN) {
            float4 v = *(const float4*)&x[(size_t)nn * 64 + (i & 15) * 4];
            float d = rsqrtf((float)lh[nl] + 1.0f);
            o.x = pack_bf16x2(v.x * d, v.y * d);
            o.y = pack_bf16x2(v.z * d, v.w * d);
        }
        *(uint2*)&xb[(size_t)nn * 64 + (i & 15) * 4] = o;
    }
}

// ===== MFMA GEMM: row-major in/out. EPI 0: *dinv[row] (pre-scale for gather).
//       EPI 1: relu(acc + bias) (layer-1 post-agg), pad rows stored as 0. =====
#define LSTRIDE 130
template <int K, int EPI>
__global__ __launch_bounds__(256) void gemm_mfma_kernel(const unsigned short* __restrict__ hb,
                                                        const unsigned short* __restrict__ Wt,
                                                        const float* __restrict__ dinv,
                                                        const float* __restrict__ bias,
                                                        unsigned int* __restrict__ outu) {
    __shared__ float ls[64 * LSTRIDE];  // ~33 KB
    const int wave = threadIdx.x >> 6, lane = threadIdx.x & 63;
    const int m15 = lane & 15, quad = lane >> 4;
    const int row0 = blockIdx.x * 64;
    const int arow = row0 + wave * 16 + m15;

    bf16x8 a[K / 32];
#pragma unroll
    for (int ks = 0; ks < K / 32; ks++)
        a[ks] = *(const bf16x8*)&hb[(size_t)arow * K + ks * 32 + quad * 8];

    const int lrow = wave * 16 + quad * 4;
    float dv[4];
    if (EPI == 0) {
#pragma unroll
        for (int r = 0; r < 4; r++) dv[r] = dinv[row0 + lrow + r];
    }

#pragma unroll
    for (int ct = 0; ct < 8; ct++) {
        f32x4 acc = {0.f, 0.f, 0.f, 0.f};
#pragma unroll
        for (int ks = 0; ks < K / 32; ks++) {
            bf16x8 b = *(const bf16x8*)&Wt[(ct * 16 + m15) * K + ks * 32 + quad * 8];
            acc = __builtin_amdgcn_mfma_f32_16x16x32_bf16(a[ks], b, acc, 0, 0, 0);
        }
        float bv = (EPI == 1) ? bias[ct * 16 + m15] : 0.f;
#pragma unroll
        for (int r = 0; r < 4; r++) {
            float v = (EPI == 0) ? acc[r] * dv[r] : fmaxf(acc[r] + bv, 0.f);
            ls[(lrow + r) * LSTRIDE + ct * 16 + m15] = v;
        }
    }
    __syncthreads();

#pragma unroll
    for (int k = 0; k < 4; k++) {
        int idx = threadIdx.x + 256 * k;
        int row = idx >> 4, q = idx & 15;
        const float* p = &ls[row * LSTRIDE + q * 8];
        u32x4 o;
        o[0] = pack_bf16x2(p[0], p[1]);
        o[1] = pack_bf16x2(p[2], p[3]);
        o[2] = pack_bf16x2(p[4], p[5]);
        o[3] = pack_bf16x2(p[6], p[7]);
        if (EPI == 1 && row0 + row >= NN) { o[0] = o[1] = o[2] = o[3] = 0u; }
        __builtin_nontemporal_store(
            o, (u32x4*)&outu[(size_t)(row0 + row) * ROW_U + q * 4]);
    }
}

// ---- gather one node's aggregated row slice (16 B/lane; RU uints per row) ----
template <int RU>
__device__ inline void gather_row(const unsigned int* __restrict__ hwc,
                                  const int2* __restrict__ rowse,
                                  const unsigned short* __restrict__ csr,
                                  int n, int u0,
                                  f32x2& a0, f32x2& a1, f32x2& a2, f32x2& a3) {
    uint4 sv = *(const uint4*)&hwc[(size_t)n * RU + u0];  // self-loop term
    a0.x = bf_lo(sv.x); a0.y = bf_hi(sv.x);
    a1.x = bf_lo(sv.y); a1.y = bf_hi(sv.y);
    a2.x = bf_lo(sv.z); a2.y = bf_hi(sv.z);
    a3.x = bf_lo(sv.w); a3.y = bf_hi(sv.w);
    const int2 se = rowse[n];  // start/end, both multiples of 8
    int i = se.x;
    for (; i + 16 <= se.y; i += 16) {  // unroll x2: 16 gathers outstanding
        u32x4 c0 = __builtin_nontemporal_load((const u32x4*)&csr[i]);
        u32x4 c1 = __builtin_nontemporal_load((const u32x4*)&csr[i + 8]);
        int s0 = c0[0] & 0xFFFF, s1 = c0[0] >> 16;
        int s2 = c0[1] & 0xFFFF, s3 = c0[1] >> 16;
        int s4 = c0[2] & 0xFFFF, s5 = c0[2] >> 16;
        int s6 = c0[3] & 0xFFFF, s7 = c0[3] >> 16;
        int t0 = c1[0] & 0xFFFF, t1 = c1[0] >> 16;
        int t2 = c1[1] & 0xFFFF, t3 = c1[1] >> 16;
        int t4 = c1[2] & 0xFFFF, t5 = c1[2] >> 16;
        int t6 = c1[3] & 0xFFFF, t7 = c1[3] >> 16;
        uint4 v0 = *(const uint4*)&hwc[(size_t)s0 * RU + u0];
        uint4 v1 = *(const uint4*)&hwc[(size_t)s1 * RU + u0];
        uint4 v2 = *(const uint4*)&hwc[(size_t)s2 * RU + u0];
        uint4 v3 = *(const uint4*)&hwc[(size_t)s3 * RU + u0];
        uint4 v4 = *(const uint4*)&hwc[(size_t)s4 * RU + u0];
        uint4 v5 = *(const uint4*)&hwc[(size_t)s5 * RU + u0];
        uint4 v6 = *(const uint4*)&hwc[(size_t)s6 * RU + u0];
        uint4 v7 = *(const uint4*)&hwc[(size_t)s7 * RU + u0];
        uint4 w0 = *(const uint4*)&hwc[(size_t)t0 * RU + u0];
        uint4 w1 = *(const uint4*)&hwc[(size_t)t1 * RU + u0];
        uint4 w2 = *(const uint4*)&hwc[(size_t)t2 * RU + u0];
        uint4 w3 = *(const uint4*)&hwc[(size_t)t3 * RU + u0];
        uint4 w4 = *(const uint4*)&hwc[(size_t)t4 * RU + u0];
        uint4 w5 = *(const uint4*)&hwc[(size_t)t5 * RU + u0];
        uint4 w6 = *(const uint4*)&hwc[(size_t)t6 * RU + u0];
        uint4 w7 = *(const uint4*)&hwc[(size_t)t7 * RU + u0];
        pkadd(a0, v0.x); pkadd(a1, v0.y); pkadd(a2, v0.z); pkadd(a3, v0.w);
        pkadd(a0, v1.x); pkadd(a1, v1.y); pkadd(a2, v1.z); pkadd(a3, v1.w);
        pkadd(a0, v2.x); pkadd(a1, v2.y); pkadd(a2, v2.z); pkadd(a3, v2.w);
        pkadd(a0, v3.x); pkadd(a1, v3.y); pkadd(a2, v3.z); pkadd(a3, v3.w);
        pkadd(a0, v4.x); pkadd(a1, v4.y); pkadd(a2, v4.z); pkadd(a3, v4.w);
        pkadd(a0, v5.x); pkadd(a1, v5.y); pkadd(a2, v5.z); pkadd(a3, v5.w);
        pkadd(a0, v6.x); pkadd(a1, v6.y); pkadd(a2, v6.z); pkadd(a3, v6.w);
        pkadd(a0, v7.x); pkadd(a1, v7.y); pkadd(a2, v7.z); pkadd(a3, v7.w);
        pkadd(a0, w0.x); pkadd(a1, w0.y); pkadd(a2, w0.z); pkadd(a3, w0.w);
        pkadd(a0, w1.x); pkadd(a1, w1.y); pkadd(a2, w1.z); pkadd(a3, w1.w);
        pkadd(a0, w2.x); pkadd(a1, w2.y); pkadd(a2, w2.z); pkadd(a3, w2.w);
        pkadd(a0, w3.x); pkadd(a1, w3.y); pkadd(a2, w3.z); pkadd(a3, w3.w);
        pkadd(a0, w4.x); pkadd(a1, w4.y); pkadd(a2, w4.z); pkadd(a3, w4.w);
        pkadd(a0, w5.x); pkadd(a1, w5.y); pkadd(a2, w5.z); pkadd(a3, w5.w);
        pkadd(a0, w6.x); pkadd(a1, w6.y); pkadd(a2, w6.z); pkadd(a3, w6.w);
        pkadd(a0, w7.x); pkadd(a1, w7.y); pkadd(a2, w7.z); pkadd(a3, w7.w);
    }
    if (i < se.y) {  // remainder is exactly one 8-group
        u32x4 c = __builtin_nontemporal_load((const u32x4*)&csr[i]);
        int s0 = c[0] & 0xFFFF, s1 = c[0] >> 16;
        int s2 = c[1] & 0xFFFF, s3 = c[1] >> 16;
        int s4 = c[2] & 0xFFFF, s5 = c[2] >> 16;
        int s6 = c[3] & 0xFFFF, s7 = c[3] >> 16;
        uint4 v0 = *(const uint4*)&hwc[(size_t)s0 * RU + u0];
        uint4 v1 = *(const uint4*)&hwc[(size_t)s1 * RU + u0];
        uint4 v2 = *(const uint4*)&hwc[(size_t)s2 * RU + u0];
        uint4 v3 = *(const uint4*)&hwc[(size_t)s3 * RU + u0];
        uint4 v4 = *(const uint4*)&hwc[(size_t)s4 * RU + u0];
        uint4 v5 = *(const uint4*)&hwc[(size_t)s5 * RU + u0];
        uint4 v6 = *(const uint4*)&hwc[(size_t)s6 * RU + u0];
        uint4 v7 = *(const uint4*)&hwc[(size_t)s7 * RU + u0];
        pkadd(a0, v0.x); pkadd(a1, v0.y); pkadd(a2, v0.z); pkadd(a3, v0.w);
        pkadd(a0, v1.x); pkadd(a1, v1.y); pkadd(a2, v1.z); pkadd(a3, v1.w);
        pkadd(a0, v2.x); pkadd(a1, v2.y); pkadd(a2, v2.z); pkadd(a3, v2.w);
        pkadd(a0, v3.x); pkadd(a1, v3.y); pkadd(a2, v3.z); pkadd(a3, v3.w);
        pkadd(a0, v4.x); pkadd(a1, v4.y); pkadd(a2, v4.z); pkadd(a3, v4.w);
        pkadd(a0, v5.x); pkadd(a1, v5.y); pkadd(a2, v5.z); pkadd(a3, v5.w);
        pkadd(a0, v6.x); pkadd(a1, v6.y); pkadd(a2, v6.z); pkadd(a3, v6.w);
        pkadd(a0, v7.x); pkadd(a1, v7.y); pkadd(a2, v7.z); pkadd(a3, v7.w);
    }
}

// ====== agg_x: layer-1 pre-aggregation on 64-dim x-hat rows (1 transaction/edge) ======
// 8 lanes/node, 32 nodes/block. out = (self + sum) * dinv[n], bf16.
__global__ __launch_bounds__(256) void aggx_kernel(const unsigned int* __restrict__ xbu,
                                                   const int2* __restrict__ rowse,
                                                   const unsigned short* __restrict__ csr,
                                                   const float* __restrict__ dinv,
                                                   unsigned int* __restrict__ xa) {
    const int u0 = (threadIdx.x & 7) * 4;
    const int n = blockIdx.x * 32 + (threadIdx.x >> 3);
    f32x2 a0, a1, a2, a3;
    gather_row<XROW_U>(xbu, rowse, csr, n, u0, a0, a1, a2, a3);
    const float d = dinv[n];
    u32x4 o;
    o[0] = pack_bf16x2(a0.x * d, a0.y * d);
    o[1] = pack_bf16x2(a1.x * d, a1.y * d);
    o[2] = pack_bf16x2(a2.x * d, a2.y * d);
    o[3] = pack_bf16x2(a3.x * d, a3.y * d);
    __builtin_nontemporal_store(o, (u32x4*)&xa[(size_t)n * XROW_U + u0]);
}

// ====== full-row gather aggregation (128-dim): 16 lanes/node ======
// MODE 0: relu(a*d + bias) -> bf16 (agg2).  MODE 2: relu(a*d + bias)*d (agg3, pre-scaled
// for layer-4 gather).  MODE 1: pooled (layer 4, no gemm): gather, *d, pool atomics.
template <int MODE>
__global__ __launch_bounds__(256) void agg_kernel(const unsigned int* __restrict__ hwc,
                                                  const int2* __restrict__ rowse,
                                                  const unsigned short* __restrict__ csr,
                                                  const float* __restrict__ dinv,
                                                  const float* __restrict__ bias,
                                                  const int* __restrict__ batch,
                                                  float* __restrict__ poolpart,
                                                  unsigned int* __restrict__ outc) {
    const int u = threadIdx.x & 15;
    const int u0 = u * 4;
    if (MODE != 1) {
        const int n = blockIdx.x * 16 + (threadIdx.x >> 4);
        f32x2 a0, a1, a2, a3;
        gather_row<ROW_U>(hwc, rowse, csr, n, u0, a0, a1, a2, a3);
        const float d = dinv[n];
        const float2* bp = (const float2*)bias + u0;
        float2 q0 = bp[0], q1 = bp[1], q2 = bp[2], q3 = bp[3];
        float r0 = fmaxf(a0.x * d + q0.x, 0.f), r1 = fmaxf(a0.y * d + q0.y, 0.f);
        float r2 = fmaxf(a1.x * d + q1.x, 0.f), r3 = fmaxf(a1.y * d + q1.y, 0.f);
        float r4 = fmaxf(a2.x * d + q2.x, 0.f), r5 = fmaxf(a2.y * d + q2.y, 0.f);
        float r6 = fmaxf(a3.x * d + q3.x, 0.f), r7 = fmaxf(a3.y * d + q3.y, 0.f);
        if (MODE == 2) {  // pre-scale for the gemm-free layer-4 gather
            r0 *= d; r1 *= d; r2 *= d; r3 *= d;
            r4 *= d; r5 *= d; r6 *= d; r7 *= d;
        }
        u32x4 o;
        o[0] = pack_bf16x2(r0, r1);
        o[1] = pack_bf16x2(r2, r3);
        o[2] = pack_bf16x2(r4, r5);
        o[3] = pack_bf16x2(r6, r7);
        __builtin_nontemporal_store(o, (u32x4*)&outc[(size_t)n * ROW_U + u0]);
        return;
    }
    // ---- MODE 1: layer-4 aggregation + pooling ----
    __shared__ float lds[4][128];
    const int nip = threadIdx.x >> 4;  // node-in-pass 0..15
    const int lane = threadIdx.x & 63, wave = threadIdx.x >> 6;
    const int n0 = blockIdx.x * 64;
    const int copy = blockIdx.x & (NPART - 1);
    const int gfirst0 = batch[n0];
    const bool blockUni = (gfirst0 == batch[min(n0 + 63, NN - 1)]);
    float* __restrict__ ppb = poolpart + copy * (NG * H);
    f32x2 acc0 = {0.f, 0.f}, acc1 = {0.f, 0.f}, acc2 = {0.f, 0.f}, acc3 = {0.f, 0.f};
#pragma unroll
    for (int p = 0; p < 4; p++) {
        const int n = n0 + p * 16 + nip;
        f32x2 t0, t1, t2, t3;
        gather_row<ROW_U>(hwc, rowse, csr, n, u0, t0, t1, t2, t3);
        const float d = dinv[n];  // 0 for pad rows -> they vanish
        t0 *= d; t1 *= d; t2 *= d; t3 *= d;
        if (blockUni) {
            acc0 += t0; acc1 += t1; acc2 += t2; acc3 += t3;
        } else {  // rare graph-boundary block (<=15 of 782)
            const int gb = batch[min(n, NN - 1)];
            const bool uni = (__shfl(gb, 0) == __shfl(gb, 63));
            if (uni) {
                bfly(t0, 16); bfly(t1, 16); bfly(t2, 16); bfly(t3, 16);
                bfly(t0, 32); bfly(t1, 32); bfly(t2, 32); bfly(t3, 32);
                if (lane < 16) {
                    float* q = ppb + __shfl(gb, 0) * H + lane * 8;
                    atomicAdd(&q[0], t0.x); atomicAdd(&q[1], t0.y);
                    atomicAdd(&q[2], t1.x); atomicAdd(&q[3], t1.y);
                    atomicAdd(&q[4], t2.x); atomicAdd(&q[5], t2.y);
                    atomicAdd(&q[6], t3.x); atomicAdd(&q[7], t3.y);
                }
            } else if (n < NN) {
                float* q = ppb + gb * H + u * 8;
                atomicAdd(&q[0], t0.x); atomicAdd(&q[1], t0.y);
                atomicAdd(&q[2], t1.x); atomicAdd(&q[3], t1.y);
                atomicAdd(&q[4], t2.x); atomicAdd(&q[5], t2.y);
                atomicAdd(&q[6], t3.x); atomicAdd(&q[7], t3.y);
            }
        }
    }
    if (blockUni) {
        bfly(acc0, 16); bfly(acc1, 16); bfly(acc2, 16); bfly(acc3, 16);
        bfly(acc0, 32); bfly(acc1, 32); bfly(acc2, 32); bfly(acc3, 32);
        if (lane < 16) {
            float* q = &lds[wave][lane * 8];
            q[0] = acc0.x; q[1] = acc0.y;
            q[2] = acc1.x; q[3] = acc1.y;
            q[4] = acc2.x; q[5] = acc2.y;
            q[6] = acc3.x; q[7] = acc3.y;
        }
        __syncthreads();
        if (threadIdx.x < 128) {
            float tot = lds[0][threadIdx.x] + lds[1][threadIdx.x] +
                        lds[2][threadIdx.x] + lds[3][threadIdx.x];
            atomicAdd(&ppb[gfirst0 * H + threadIdx.x], tot);
        }
    }
}

// ===== final MLP: reduce NPART copies -> mean -> @W4+b4 -> @lw1 relu -> @lw2 =====
__global__ __launch_bounds__(1024) void mlp_kernel(const float* __restrict__ poolpart,
                                                   const int* __restrict__ pcnt,
                                                   const float* __restrict__ W4,
                                                   const float* __restrict__ b4,
                                                   const float* __restrict__ lw1,
                                                   const float* __restrict__ lb1,
                                                   const float* __restrict__ lw2,
                                                   const float* __restrict__ lb2,
                                                   float* __restrict__ out) {
    __shared__ float mean_s[NG * H];
    __shared__ float z_s[NG * H];
    __shared__ float cnt_s[NG];
    __shared__ float hid_s[NG * 64];
    int tid = threadIdx.x;
    if (tid < NG) cnt_s[tid] = fmaxf((float)pcnt[tid], 1.0f);
    __syncthreads();
    for (int i = tid; i < NG * H; i += 1024) {
        float s = 0.f;
        for (int p = 0; p < NPART; p++) s += poolpart[p * (NG * H) + i];
        mean_s[i] = s / cnt_s[i >> 7];
    }
    __syncthreads();
#pragma unroll
    for (int r = 0; r < 2; r++) {
        int i = tid + r * 1024;
        int g = i >> 7, j = i & (H - 1);
        float acc = b4[j];
        for (int f = 0; f < H; f++) acc += mean_s[g * H + f] * W4[f * H + j];
        z_s[i] = acc;
    }
    __syncthreads();
    {
        int g = tid >> 6, j = tid & 63;
        float acc = lb1[j];
        for (int f = 0; f < H; f++) acc += z_s[g * H + f] * lw1[f * 64 + j];
        hid_s[g * 64 + j] = fmaxf(acc, 0.f);
    }
    __syncthreads();
    if (tid < 32) {
        int g = tid >> 1, c = tid & 1;
        float acc = lb2[c];
        for (int j = 0; j < 64; j++) acc += hid_s[g * 64 + j] * lw2[j * 2 + c];
        out[g * 2 + c] = acc;
    }
}

extern "C" void kernel_launch(void* const* d_in, const int* in_sizes, int n_in,
                              void* d_out, int out_size, void* d_ws, size_t ws_size,
                              hipStream_t stream) {
    const float* x = (const float*)d_in[0];
    const int* ei = (const int*)d_in[1];
    const int* batch = (const int*)d_in[2];
    const float* W1 = (const float*)d_in[3];
    const float* b1 = (const float*)d_in[4];
    const float* W2 = (const float*)d_in[5];
    const float* b2 = (const float*)d_in[6];
    const float* W3 = (const float*)d_in[7];
    const float* b3 = (const float*)d_in[8];
    const float* W4 = (const float*)d_in[9];
    const float* b4 = (const float*)d_in[10];
    const float* lw1 = (const float*)d_in[11];
    const float* lb1 = (const float*)d_in[12];
    const float* lw2 = (const float*)d_in[13];
    const float* lb2 = (const float*)d_in[14];
    float* out = (float*)d_out;

    // workspace layout (4-byte units; sizes annotated in ints); ~39.5 MB
    int* wsi = (int*)d_ws;
    int* gcount = wsi;                                      // @0        256
    int* galloc = wsi + 256;                                // @256      1
    int* pcnt = wsi + 280;                                  // @280      16 (zeroed to 512)
    float* poolpart = (float*)(wsi + 512);                  // @512      131072 (NPART*NG*H)
    int2* rowse = (int2*)(wsi + 131584);                    // @131584   100096 (NPAD int2)
    unsigned short* csr = (unsigned short*)(wsi + 231680);  // @231680   600000 (1.2M ushorts)
    float* dinv = (float*)(wsi + 831680);                   // @831680   50048
    unsigned short* Wt1 = (unsigned short*)(wsi + 881728);  // @881728   4096 (8192 shorts)
    unsigned short* Wt2 = (unsigned short*)(wsi + 885824);  // @885824   8192 (16384 shorts)
    unsigned short* Wt3 = (unsigned short*)(wsi + 894016);  // @894016   8192
    unsigned short* xb = (unsigned short*)(wsi + 910400);   // @910400   1601536 (NPAD*64 shorts)
    unsigned int* hb = (unsigned int*)(wsi + 2511936);      // @2511936  3203072 (NPAD*64 uints)
    unsigned int* hwb = (unsigned int*)(wsi + 5715008);     // @5715008  3203072 (also holds xa)
    unsigned int* ebuf = (unsigned int*)(wsi + 8918080);    // @8918080  940800 -> ends 9858880

    const int gemmBlocks = NPAD / 64;          // 782
    const int aggxBlocks = NPAD / 32;          // 1564 (32 nodes/block, 64-dim rows)
    const int agg0Blocks = NPAD / 16;          // 3128 (16 nodes/block, 128-dim rows)
    const int poolBlocks = NPAD / 64;          // 782 (64 nodes/block, pooled)

    // ---- zero control vars (tiny); pool partials zeroed inside prep ----
    hipMemsetAsync(wsi, 0, 512 * sizeof(int), stream);
    fillA_prep_kernel<<<FILLA_BLOCKS + PREP_BLOCKS, 256, 0, stream>>>(
        ei, gcount, ebuf, W1, W2, W3, Wt1, Wt2, Wt3, (int4*)poolpart);
    fillB_kernel<<<NBUCK, 256, 0, stream>>>(ebuf, gcount, galloc, pcnt, batch, x,
                                            rowse, dinv, xb, csr);

    // ---- layer 1: pre-aggregate x-hat (64-dim), then GEMM with relu+b1 ----
    aggx_kernel<<<aggxBlocks, 256, 0, stream>>>((const unsigned int*)xb, rowse, csr,
                                                dinv, hwb);  // xa lives in hwb
    gemm_mfma_kernel<FIN, 1><<<gemmBlocks, 256, 0, stream>>>((unsigned short*)hwb, Wt1,
                                                             nullptr, b1, hb);
    // ---- layer 2 ----
    gemm_mfma_kernel<H, 0><<<gemmBlocks, 256, 0, stream>>>((unsigned short*)hb, Wt2,
                                                           dinv, nullptr, hwb);
    agg_kernel<0><<<agg0Blocks, 256, 0, stream>>>(hwb, rowse, csr, dinv, b2, batch,
                                                  nullptr, hb);
    // ---- layer 3 (epilogue pre-scales by dinv for the gemm-free layer 4) ----
    gemm_mfma_kernel<H, 0><<<gemmBlocks, 256, 0, stream>>>((unsigned short*)hb, Wt3,
                                                           dinv, nullptr, hwb);
    agg_kernel<2><<<agg0Blocks, 256, 0, stream>>>(hwb, rowse, csr, dinv, b3, batch,
                                                  nullptr, hb);
    // ---- layer 4: aggregation + pooling directly on h3' (W4 folded into MLP) ----
    agg_kernel<1><<<poolBlocks, 256, 0, stream>>>(hb, rowse, csr, dinv, nullptr, batch,
                                                  poolpart, nullptr);

    // ---- final MLP (applies W4, b4, then the classifier) ----
    mlp_kernel<<<1, 1024, 0, stream>>>(poolpart, pcnt, W4, b4, lw1, lb1, lw2, lb2, out);
}

// Round 12
// 288.708 us; speedup vs baseline: 1.0323x; 1.0172x over previous
//
#include <hip/hip_runtime.h>

#define NN 50000
#define NPAD 50048   // rows padded to multiple of 64 for MFMA tiles
#define NE 800000
#define FIN 64
#define H 128
#define NG 16
#define NPART 64         // private pooled-accumulator copies (atomic spreading)
#define NBUCK 196        // buckets of 256 dst nodes
#define BUCK_CAP 4800    // edges per bucket capacity (expected 4096 +- 64)
#define FILLA_BLOCKS 512
#define FILLA_CHUNK 1563  // ceil(NE / FILLA_BLOCKS)
#define ROW_U 64         // uints per node row (128 bf16 feats, 256 B)
#define XROW_U 32        // uints per x row (64 bf16 feats, 128 B)
#define DUMMY NN         // zero pad row used for CSR padding
#define ZERO_I4 32768    // int4s to zero: poolpart = 131072 ints
#define PREP_ITEMS (H * FIN + 2 * H * H + ZERO_I4)
#define PREP_BLOCKS ((PREP_ITEMS + 255) / 256)

typedef __bf16 bf16x8 __attribute__((ext_vector_type(8)));
typedef float f32x4 __attribute__((ext_vector_type(4)));
typedef float f32x2 __attribute__((ext_vector_type(2)));
typedef unsigned int u32x4 __attribute__((ext_vector_type(4)));

// ---- helpers ----
__device__ inline unsigned short bf16r(float x) {
    unsigned int u = __float_as_uint(x);
    return (unsigned short)((u + 0x7fffu + ((u >> 16) & 1u)) >> 16);
}
__device__ inline unsigned int pack_bf16x2(float a, float b) {
    return (unsigned int)bf16r(a) | ((unsigned int)bf16r(b) << 16);
}
__device__ inline float bf_lo(unsigned int u) { return __uint_as_float(u << 16); }
__device__ inline float bf_hi(unsigned int u) { return __uint_as_float(u & 0xffff0000u); }

// packed fp32 add: acc(pair) += {lo(u), hi(u)}
__device__ inline void pkadd(f32x2& a, unsigned int u) {
    f32x2 p;
    p.x = bf_lo(u);
    p.y = bf_hi(u);
    asm("v_pk_add_f32 %0, %1, %0" : "+v"(a) : "v"(p));
}
__device__ inline void bfly(f32x2& a, int m) {
    a.x += __shfl_xor(a.x, m);
    a.y += __shfl_xor(a.y, m);
}

// ====== fillA + prep merged: blocks [0,512) bucket edges; rest convert W + zero pool ======
__global__ __launch_bounds__(256) void fillA_prep_kernel(const int* __restrict__ ei,
                                                         int* __restrict__ gcount,
                                                         unsigned int* __restrict__ ebuf,
                                                         const float* __restrict__ W1,
                                                         const float* __restrict__ W2,
                                                         const float* __restrict__ W3,
                                                         unsigned short* __restrict__ Wt1,
                                                         unsigned short* __restrict__ Wt2,
                                                         unsigned short* __restrict__ Wt3,
                                                         int4* __restrict__ zbuf) {
    const int t = threadIdx.x;
    if (blockIdx.x >= FILLA_BLOCKS) {
        // ---- prep part ----
        int e = (blockIdx.x - FILLA_BLOCKS) * 256 + t;
        if (e < H * FIN) {
            int n = e / FIN, k = e % FIN;
            Wt1[e] = bf16r(W1[k * H + n]);
            return;
        }
        int u = e - H * FIN;
        if (u < 2 * H * H) {
            const float* W = W2;
            unsigned short* Wt = Wt2;
            if (u >= H * H) { W = W3; Wt = Wt3; u -= H * H; }
            int n = u / H, k = u % H;
            Wt[u] = bf16r(W[k * H + n]);
            return;
        }
        int z = u - 2 * H * H;
        if (z < ZERO_I4) zbuf[z] = make_int4(0, 0, 0, 0);  // zero pool partials
        return;
    }
    // ---- fillA part: histogram into 196 buckets of 256 nodes ----
    __shared__ int hist[256];
    __shared__ int base[256];
    hist[t] = 0;
    __syncthreads();
    const int e0 = blockIdx.x * FILLA_CHUNK;
    const int e1 = min(e0 + FILLA_CHUNK, NE);
    for (int e = e0 + t; e < e1; e += 256)
        atomicAdd(&hist[ei[NE + e] >> 8], 1);
    __syncthreads();
    {
        int h = hist[t];
        base[t] = h ? atomicAdd(&gcount[t], h) : 0;
    }
    __syncthreads();
    for (int e = e0 + t; e < e1; e += 256) {
        int d = ei[NE + e];
        int s = ei[e];
        int b = d >> 8;
        int pos = atomicAdd(&base[b], 1);
        ebuf[b * BUCK_CAP + pos] = (unsigned int)s | ((unsigned int)d << 16);
    }
}

// fillB (fused hist+scan+scatter), 196 blocks, 1 node per thread.
// Also: per-graph node counts (pcnt) and fused xprep (xb = bf16(x*dinv)).
__global__ __launch_bounds__(256) void fillB_kernel(const unsigned int* __restrict__ ebuf,
                                                    const int* __restrict__ gcount,
                                                    int* __restrict__ galloc,
                                                    int* __restrict__ pcnt,
                                                    const int* __restrict__ batch,
                                                    const float* __restrict__ x,
                                                    int2* __restrict__ rowse,
                                                    float* __restrict__ dinv,
                                                    unsigned short* __restrict__ xb,
                                                    unsigned short* __restrict__ csr) {
    __shared__ int lh[256];
    __shared__ int lsum[256];
    __shared__ int lcur[256];
    __shared__ int lgc[16];
    __shared__ int base_s;
    const int b = blockIdx.x, t = threadIdx.x;
    const int n0 = b * 256;
    lh[t] = 0;
    if (t < 16) lgc[t] = 0;
    __syncthreads();
    const int ne = gcount[b];
    const unsigned int* __restrict__ eb = ebuf + b * BUCK_CAP;
    for (int i = t; i < ne; i += 256)
        atomicAdd(&lh[(int)(eb[i] >> 16) - n0], 1);
    __syncthreads();
    const int c = lh[t];
    const int p = (c + 7) & ~7;
    const int n = n0 + t;
    if (n < NN) atomicAdd(&lgc[batch[n]], 1);
    lsum[t] = p;
    __syncthreads();
    if (t < 16 && lgc[t]) atomicAdd(&pcnt[t], lgc[t]);
    for (int off = 1; off < 256; off <<= 1) {
        int u = (t >= off) ? lsum[t - off] : 0;
        __syncthreads();
        lsum[t] += u;
        __syncthreads();
    }
    if (t == 255) base_s = atomicAdd(galloc, lsum[255]);
    const int excl = t ? lsum[t - 1] : 0;
    __syncthreads();
    const int st = base_s + excl;
    if (n < NN) {
        rowse[n] = make_int2(st, st + p);
        dinv[n] = rsqrtf((float)c + 1.0f);  // +1 self-loop
    } else if (n < NPAD) {
        rowse[n] = make_int2(0, 0);
        dinv[n] = 0.0f;
    }
    lcur[t] = st;
    __syncthreads();
    for (int i = t; i < ne; i += 256) {
        unsigned int u = eb[i];
        int pos = atomicAdd(&lcur[(int)(u >> 16) - n0], 1);
        csr[pos] = (unsigned short)(u & 0xFFFFu);
    }
    __syncthreads();
    for (int k = st + c; k < st + p; k++) csr[k] = (unsigned short)DUMMY;
    // ---- fused xprep: this block's 256 rows, xb = bf16(x * dinv); pads zero ----
    for (int i = t; i < 4096; i += 256) {  // 256 rows x 16 float4
        int nl = i >> 4;
        int nn = n0 + nl;
        if (nn >= NPAD) continue;
        uint2 o = make_uint2(0u, 0u);
        if (nn < NN) {
            float4 v = *(const float4*)&x[(size_t)nn * 64 + (i & 15) * 4];
            float d = rsqrtf((float)lh[nl] + 1.0f);
            o.x = pack_bf16x2(v.x * d, v.y * d);
            o.y = pack_bf16x2(v.z * d, v.w * d);
        }
        *(uint2*)&xb[(size_t)nn * 64 + (i & 15) * 4] = o;
    }
}

#define LSTRIDE 130

// ===== gemm12 fused (row-local): hw2' = (relu(xa@W1 + b1) @ W2) * dinv =====
// H1 never touches global memory; bf16 rounding of H1 identical to the unfused path.
__global__ __launch_bounds__(256) void gemm12_kernel(const unsigned short* __restrict__ xa,
                                                     const unsigned short* __restrict__ Wt1,
                                                     const unsigned short* __restrict__ Wt2,
                                                     const float* __restrict__ b1,
                                                     const float* __restrict__ dinv,
                                                     unsigned int* __restrict__ outu) {
    __shared__ float ls[64 * LSTRIDE];  // ~33 KB
    const int wave = threadIdx.x >> 6, lane = threadIdx.x & 63;
    const int m15 = lane & 15, quad = lane >> 4;
    const int row0 = blockIdx.x * 64;
    const int arow = row0 + wave * 16 + m15;
    const int lrow = wave * 16 + quad * 4;

    // --- stage 1: H1 tile = relu(xa @ W1 + b1) -> LDS (f32) ---
    bf16x8 a[2];
#pragma unroll
    for (int ks = 0; ks < 2; ks++)
        a[ks] = *(const bf16x8*)&xa[(size_t)arow * FIN + ks * 32 + quad * 8];

#pragma unroll
    for (int ct = 0; ct < 8; ct++) {
        f32x4 acc = {0.f, 0.f, 0.f, 0.f};
#pragma unroll
        for (int ks = 0; ks < 2; ks++) {
            bf16x8 bfr = *(const bf16x8*)&Wt1[(ct * 16 + m15) * FIN + ks * 32 + quad * 8];
            acc = __builtin_amdgcn_mfma_f32_16x16x32_bf16(a[ks], bfr, acc, 0, 0, 0);
        }
        float bv = b1[ct * 16 + m15];
#pragma unroll
        for (int r = 0; r < 4; r++)
            ls[(lrow + r) * LSTRIDE + ct * 16 + m15] = fmaxf(acc[r] + bv, 0.f);
    }
    __syncthreads();

    // --- stage 2: read own A-fragments of H1, round to bf16 (same as old store path) ---
    bf16x8 h[4];
#pragma unroll
    for (int ks = 0; ks < 4; ks++) {
        const float* p = &ls[(wave * 16 + m15) * LSTRIDE + ks * 32 + quad * 8];
        u32x4 pk;
        pk[0] = pack_bf16x2(p[0], p[1]);
        pk[1] = pack_bf16x2(p[2], p[3]);
        pk[2] = pack_bf16x2(p[4], p[5]);
        pk[3] = pack_bf16x2(p[6], p[7]);
        h[ks] = *(bf16x8*)&pk;
    }
    __syncthreads();  // all lanes finished reading ls before overwrite

    float dv[4];
#pragma unroll
    for (int r = 0; r < 4; r++) dv[r] = dinv[row0 + lrow + r];

    // --- stage 3: hw2' = (H1 @ W2) * dinv -> LDS -> bf16 NT store ---
#pragma unroll
    for (int ct = 0; ct < 8; ct++) {
        f32x4 acc = {0.f, 0.f, 0.f, 0.f};
#pragma unroll
        for (int ks = 0; ks < 4; ks++) {
            bf16x8 bfr = *(const bf16x8*)&Wt2[(ct * 16 + m15) * H + ks * 32 + quad * 8];
            acc = __builtin_amdgcn_mfma_f32_16x16x32_bf16(h[ks], bfr, acc, 0, 0, 0);
        }
#pragma unroll
        for (int r = 0; r < 4; r++)
            ls[(lrow + r) * LSTRIDE + ct * 16 + m15] = acc[r] * dv[r];
    }
    __syncthreads();

#pragma unroll
    for (int k = 0; k < 4; k++) {
        int idx = threadIdx.x + 256 * k;
        int row = idx >> 4, q = idx & 15;
        const float* p = &ls[row * LSTRIDE + q * 8];
        u32x4 o;
        o[0] = pack_bf16x2(p[0], p[1]);
        o[1] = pack_bf16x2(p[2], p[3]);
        o[2] = pack_bf16x2(p[4], p[5]);
        o[3] = pack_bf16x2(p[6], p[7]);
        __builtin_nontemporal_store(
            o, (u32x4*)&outu[(size_t)(row0 + row) * ROW_U + q * 4]);
    }
}

// ===== MFMA GEMM (gemm3): row-major in/out, epilogue *dinv[row] =====
template <int K>
__global__ __launch_bounds__(256) void gemm_mfma_kernel(const unsigned short* __restrict__ hb,
                                                        const unsigned short* __restrict__ Wt,
                                                        const float* __restrict__ dinv,
                                                        unsigned int* __restrict__ outu) {
    __shared__ float ls[64 * LSTRIDE];  // ~33 KB
    const int wave = threadIdx.x >> 6, lane = threadIdx.x & 63;
    const int m15 = lane & 15, quad = lane >> 4;
    const int row0 = blockIdx.x * 64;
    const int arow = row0 + wave * 16 + m15;

    bf16x8 a[K / 32];
#pragma unroll
    for (int ks = 0; ks < K / 32; ks++)
        a[ks] = *(const bf16x8*)&hb[(size_t)arow * K + ks * 32 + quad * 8];

    const int lrow = wave * 16 + quad * 4;
    float dv[4];
#pragma unroll
    for (int r = 0; r < 4; r++) dv[r] = dinv[row0 + lrow + r];

#pragma unroll
    for (int ct = 0; ct < 8; ct++) {
        f32x4 acc = {0.f, 0.f, 0.f, 0.f};
#pragma unroll
        for (int ks = 0; ks < K / 32; ks++) {
            bf16x8 b = *(const bf16x8*)&Wt[(ct * 16 + m15) * K + ks * 32 + quad * 8];
            acc = __builtin_amdgcn_mfma_f32_16x16x32_bf16(a[ks], b, acc, 0, 0, 0);
        }
#pragma unroll
        for (int r = 0; r < 4; r++)
            ls[(lrow + r) * LSTRIDE + ct * 16 + m15] = acc[r] * dv[r];
    }
    __syncthreads();

#pragma unroll
    for (int k = 0; k < 4; k++) {
        int idx = threadIdx.x + 256 * k;
        int row = idx >> 4, q = idx & 15;
        const float* p = &ls[row * LSTRIDE + q * 8];
        u32x4 o;
        o[0] = pack_bf16x2(p[0], p[1]);
        o[1] = pack_bf16x2(p[2], p[3]);
        o[2] = pack_bf16x2(p[4], p[5]);
        o[3] = pack_bf16x2(p[6], p[7]);
        __builtin_nontemporal_store(
            o, (u32x4*)&outu[(size_t)(row0 + row) * ROW_U + q * 4]);
    }
}

// ---- gather one node's aggregated row slice (16 B/lane; RU uints per row) ----
template <int RU>
__device__ inline void gather_row(const unsigned int* __restrict__ hwc,
                                  const int2* __restrict__ rowse,
                                  const unsigned short* __restrict__ csr,
                                  int n, int u0,
                                  f32x2& a0, f32x2& a1, f32x2& a2, f32x2& a3) {
    uint4 sv = *(const uint4*)&hwc[(size_t)n * RU + u0];  // self-loop term
    a0.x = bf_lo(sv.x); a0.y = bf_hi(sv.x);
    a1.x = bf_lo(sv.y); a1.y = bf_hi(sv.y);
    a2.x = bf_lo(sv.z); a2.y = bf_hi(sv.z);
    a3.x = bf_lo(sv.w); a3.y = bf_hi(sv.w);
    const int2 se = rowse[n];  // start/end, both multiples of 8
    int i = se.x;
    for (; i + 16 <= se.y; i += 16) {  // unroll x2: 16 gathers outstanding
        u32x4 c0 = __builtin_nontemporal_load((const u32x4*)&csr[i]);
        u32x4 c1 = __builtin_nontemporal_load((const u32x4*)&csr[i + 8]);
        int s0 = c0[0] & 0xFFFF, s1 = c0[0] >> 16;
        int s2 = c0[1] & 0xFFFF, s3 = c0[1] >> 16;
        int s4 = c0[2] & 0xFFFF, s5 = c0[2] >> 16;
        int s6 = c0[3] & 0xFFFF, s7 = c0[3] >> 16;
        int t0 = c1[0] & 0xFFFF, t1 = c1[0] >> 16;
        int t2 = c1[1] & 0xFFFF, t3 = c1[1] >> 16;
        int t4 = c1[2] & 0xFFFF, t5 = c1[2] >> 16;
        int t6 = c1[3] & 0xFFFF, t7 = c1[3] >> 16;
        uint4 v0 = *(const uint4*)&hwc[(size_t)s0 * RU + u0];
        uint4 v1 = *(const uint4*)&hwc[(size_t)s1 * RU + u0];
        uint4 v2 = *(const uint4*)&hwc[(size_t)s2 * RU + u0];
        uint4 v3 = *(const uint4*)&hwc[(size_t)s3 * RU + u0];
        uint4 v4 = *(const uint4*)&hwc[(size_t)s4 * RU + u0];
        uint4 v5 = *(const uint4*)&hwc[(size_t)s5 * RU + u0];
        uint4 v6 = *(const uint4*)&hwc[(size_t)s6 * RU + u0];
        uint4 v7 = *(const uint4*)&hwc[(size_t)s7 * RU + u0];
        uint4 w0 = *(const uint4*)&hwc[(size_t)t0 * RU + u0];
        uint4 w1 = *(const uint4*)&hwc[(size_t)t1 * RU + u0];
        uint4 w2 = *(const uint4*)&hwc[(size_t)t2 * RU + u0];
        uint4 w3 = *(const uint4*)&hwc[(size_t)t3 * RU + u0];
        uint4 w4 = *(const uint4*)&hwc[(size_t)t4 * RU + u0];
        uint4 w5 = *(const uint4*)&hwc[(size_t)t5 * RU + u0];
        uint4 w6 = *(const uint4*)&hwc[(size_t)t6 * RU + u0];
        uint4 w7 = *(const uint4*)&hwc[(size_t)t7 * RU + u0];
        pkadd(a0, v0.x); pkadd(a1, v0.y); pkadd(a2, v0.z); pkadd(a3, v0.w);
        pkadd(a0, v1.x); pkadd(a1, v1.y); pkadd(a2, v1.z); pkadd(a3, v1.w);
        pkadd(a0, v2.x); pkadd(a1, v2.y); pkadd(a2, v2.z); pkadd(a3, v2.w);
        pkadd(a0, v3.x); pkadd(a1, v3.y); pkadd(a2, v3.z); pkadd(a3, v3.w);
        pkadd(a0, v4.x); pkadd(a1, v4.y); pkadd(a2, v4.z); pkadd(a3, v4.w);
        pkadd(a0, v5.x); pkadd(a1, v5.y); pkadd(a2, v5.z); pkadd(a3, v5.w);
        pkadd(a0, v6.x); pkadd(a1, v6.y); pkadd(a2, v6.z); pkadd(a3, v6.w);
        pkadd(a0, v7.x); pkadd(a1, v7.y); pkadd(a2, v7.z); pkadd(a3, v7.w);
        pkadd(a0, w0.x); pkadd(a1, w0.y); pkadd(a2, w0.z); pkadd(a3, w0.w);
        pkadd(a0, w1.x); pkadd(a1, w1.y); pkadd(a2, w1.z); pkadd(a3, w1.w);
        pkadd(a0, w2.x); pkadd(a1, w2.y); pkadd(a2, w2.z); pkadd(a3, w2.w);
        pkadd(a0, w3.x); pkadd(a1, w3.y); pkadd(a2, w3.z); pkadd(a3, w3.w);
        pkadd(a0, w4.x); pkadd(a1, w4.y); pkadd(a2, w4.z); pkadd(a3, w4.w);
        pkadd(a0, w5.x); pkadd(a1, w5.y); pkadd(a2, w5.z); pkadd(a3, w5.w);
        pkadd(a0, w6.x); pkadd(a1, w6.y); pkadd(a2, w6.z); pkadd(a3, w6.w);
        pkadd(a0, w7.x); pkadd(a1, w7.y); pkadd(a2, w7.z); pkadd(a3, w7.w);
    }
    if (i < se.y) {  // remainder is exactly one 8-group
        u32x4 c = __builtin_nontemporal_load((const u32x4*)&csr[i]);
        int s0 = c[0] & 0xFFFF, s1 = c[0] >> 16;
        int s2 = c[1] & 0xFFFF, s3 = c[1] >> 16;
        int s4 = c[2] & 0xFFFF, s5 = c[2] >> 16;
        int s6 = c[3] & 0xFFFF, s7 = c[3] >> 16;
        uint4 v0 = *(const uint4*)&hwc[(size_t)s0 * RU + u0];
        uint4 v1 = *(const uint4*)&hwc[(size_t)s1 * RU + u0];
        uint4 v2 = *(const uint4*)&hwc[(size_t)s2 * RU + u0];
        uint4 v3 = *(const uint4*)&hwc[(size_t)s3 * RU + u0];
        uint4 v4 = *(const uint4*)&hwc[(size_t)s4 * RU + u0];
        uint4 v5 = *(const uint4*)&hwc[(size_t)s5 * RU + u0];
        uint4 v6 = *(const uint4*)&hwc[(size_t)s6 * RU + u0];
        uint4 v7 = *(const uint4*)&hwc[(size_t)s7 * RU + u0];
        pkadd(a0, v0.x); pkadd(a1, v0.y); pkadd(a2, v0.z); pkadd(a3, v0.w);
        pkadd(a0, v1.x); pkadd(a1, v1.y); pkadd(a2, v1.z); pkadd(a3, v1.w);
        pkadd(a0, v2.x); pkadd(a1, v2.y); pkadd(a2, v2.z); pkadd(a3, v2.w);
        pkadd(a0, v3.x); pkadd(a1, v3.y); pkadd(a2, v3.z); pkadd(a3, v3.w);
        pkadd(a0, v4.x); pkadd(a1, v4.y); pkadd(a2, v4.z); pkadd(a3, v4.w);
        pkadd(a0, v5.x); pkadd(a1, v5.y); pkadd(a2, v5.z); pkadd(a3, v5.w);
        pkadd(a0, v6.x); pkadd(a1, v6.y); pkadd(a2, v6.z); pkadd(a3, v6.w);
        pkadd(a0, v7.x); pkadd(a1, v7.y); pkadd(a2, v7.z); pkadd(a3, v7.w);
    }
}

// ====== agg_x: layer-1 pre-aggregation on 64-dim x-hat rows (1 transaction/edge) ======
// 8 lanes/node, 32 nodes/block. out = (self + sum) * dinv[n], bf16.
__global__ __launch_bounds__(256) void aggx_kernel(const unsigned int* __restrict__ xbu,
                                                   const int2* __restrict__ rowse,
                                                   const unsigned short* __restrict__ csr,
                                                   const float* __restrict__ dinv,
                                                   unsigned int* __restrict__ xa) {
    const int u0 = (threadIdx.x & 7) * 4;
    const int n = blockIdx.x * 32 + (threadIdx.x >> 3);
    f32x2 a0, a1, a2, a3;
    gather_row<XROW_U>(xbu, rowse, csr, n, u0, a0, a1, a2, a3);
    const float d = dinv[n];
    u32x4 o;
    o[0] = pack_bf16x2(a0.x * d, a0.y * d);
    o[1] = pack_bf16x2(a1.x * d, a1.y * d);
    o[2] = pack_bf16x2(a2.x * d, a2.y * d);
    o[3] = pack_bf16x2(a3.x * d, a3.y * d);
    __builtin_nontemporal_store(o, (u32x4*)&xa[(size_t)n * XROW_U + u0]);
}

// ====== full-row gather aggregation (128-dim): 16 lanes/node ======
// MODE 0: relu(a*d + bias) -> bf16 (agg2).  MODE 2: relu(a*d + bias)*d (agg3, pre-scaled
// for layer-4 gather).  MODE 1: pooled (layer 4, no gemm): gather, *d, pool atomics.
template <int MODE>
__global__ __launch_bounds__(256) void agg_kernel(const unsigned int* __restrict__ hwc,
                                                  const int2* __restrict__ rowse,
                                                  const unsigned short* __restrict__ csr,
                                                  const float* __restrict__ dinv,
                                                  const float* __restrict__ bias,
                                                  const int* __restrict__ batch,
                                                  float* __restrict__ poolpart,
                                                  unsigned int* __restrict__ outc) {
    const int u = threadIdx.x & 15;
    const int u0 = u * 4;
    if (MODE != 1) {
        const int n = blockIdx.x * 16 + (threadIdx.x >> 4);
        f32x2 a0, a1, a2, a3;
        gather_row<ROW_U>(hwc, rowse, csr, n, u0, a0, a1, a2, a3);
        const float d = dinv[n];
        const float2* bp = (const float2*)bias + u0;
        float2 q0 = bp[0], q1 = bp[1], q2 = bp[2], q3 = bp[3];
        float r0 = fmaxf(a0.x * d + q0.x, 0.f), r1 = fmaxf(a0.y * d + q0.y, 0.f);
        float r2 = fmaxf(a1.x * d + q1.x, 0.f), r3 = fmaxf(a1.y * d + q1.y, 0.f);
        float r4 = fmaxf(a2.x * d + q2.x, 0.f), r5 = fmaxf(a2.y * d + q2.y, 0.f);
        float r6 = fmaxf(a3.x * d + q3.x, 0.f), r7 = fmaxf(a3.y * d + q3.y, 0.f);
        if (MODE == 2) {  // pre-scale for the gemm-free layer-4 gather
            r0 *= d; r1 *= d; r2 *= d; r3 *= d;
            r4 *= d; r5 *= d; r6 *= d; r7 *= d;
        }
        u32x4 o;
        o[0] = pack_bf16x2(r0, r1);
        o[1] = pack_bf16x2(r2, r3);
        o[2] = pack_bf16x2(r4, r5);
        o[3] = pack_bf16x2(r6, r7);
        __builtin_nontemporal_store(o, (u32x4*)&outc[(size_t)n * ROW_U + u0]);
        return;
    }
    // ---- MODE 1: layer-4 aggregation + pooling ----
    __shared__ float lds[4][128];
    const int nip = threadIdx.x >> 4;  // node-in-pass 0..15
    const int lane = threadIdx.x & 63, wave = threadIdx.x >> 6;
    const int n0 = blockIdx.x * 64;
    const int copy = blockIdx.x & (NPART - 1);
    const int gfirst0 = batch[n0];
    const bool blockUni = (gfirst0 == batch[min(n0 + 63, NN - 1)]);
    float* __restrict__ ppb = poolpart + copy * (NG * H);
    f32x2 acc0 = {0.f, 0.f}, acc1 = {0.f, 0.f}, acc2 = {0.f, 0.f}, acc3 = {0.f, 0.f};
#pragma unroll
    for (int p = 0; p < 4; p++) {
        const int n = n0 + p * 16 + nip;
        f32x2 t0, t1, t2, t3;
        gather_row<ROW_U>(hwc, rowse, csr, n, u0, t0, t1, t2, t3);
        const float d = dinv[n];  // 0 for pad rows -> they vanish
        t0 *= d; t1 *= d; t2 *= d; t3 *= d;
        if (blockUni) {
            acc0 += t0; acc1 += t1; acc2 += t2; acc3 += t3;
        } else {  // rare graph-boundary block (<=15 of 782)
            const int gb = batch[min(n, NN - 1)];
            const bool uni = (__shfl(gb, 0) == __shfl(gb, 63));
            if (uni) {
                bfly(t0, 16); bfly(t1, 16); bfly(t2, 16); bfly(t3, 16);
                bfly(t0, 32); bfly(t1, 32); bfly(t2, 32); bfly(t3, 32);
                if (lane < 16) {
                    float* q = ppb + __shfl(gb, 0) * H + lane * 8;
                    atomicAdd(&q[0], t0.x); atomicAdd(&q[1], t0.y);
                    atomicAdd(&q[2], t1.x); atomicAdd(&q[3], t1.y);
                    atomicAdd(&q[4], t2.x); atomicAdd(&q[5], t2.y);
                    atomicAdd(&q[6], t3.x); atomicAdd(&q[7], t3.y);
                }
            } else if (n < NN) {
                float* q = ppb + gb * H + u * 8;
                atomicAdd(&q[0], t0.x); atomicAdd(&q[1], t0.y);
                atomicAdd(&q[2], t1.x); atomicAdd(&q[3], t1.y);
                atomicAdd(&q[4], t2.x); atomicAdd(&q[5], t2.y);
                atomicAdd(&q[6], t3.x); atomicAdd(&q[7], t3.y);
            }
        }
    }
    if (blockUni) {
        bfly(acc0, 16); bfly(acc1, 16); bfly(acc2, 16); bfly(acc3, 16);
        bfly(acc0, 32); bfly(acc1, 32); bfly(acc2, 32); bfly(acc3, 32);
        if (lane < 16) {
            float* q = &lds[wave][lane * 8];
            q[0] = acc0.x; q[1] = acc0.y;
            q[2] = acc1.x; q[3] = acc1.y;
            q[4] = acc2.x; q[5] = acc2.y;
            q[6] = acc3.x; q[7] = acc3.y;
        }
        __syncthreads();
        if (threadIdx.x < 128) {
            float tot = lds[0][threadIdx.x] + lds[1][threadIdx.x] +
                        lds[2][threadIdx.x] + lds[3][threadIdx.x];
            atomicAdd(&ppb[gfirst0 * H + threadIdx.x], tot);
        }
    }
}

// ===== final MLP: reduce NPART copies -> mean -> @W4+b4 -> @lw1 relu -> @lw2 =====
__global__ __launch_bounds__(1024) void mlp_kernel(const float* __restrict__ poolpart,
                                                   const int* __restrict__ pcnt,
                                                   const float* __restrict__ W4,
                                                   const float* __restrict__ b4,
                                                   const float* __restrict__ lw1,
                                                   const float* __restrict__ lb1,
                                                   const float* __restrict__ lw2,
                                                   const float* __restrict__ lb2,
                                                   float* __restrict__ out) {
    __shared__ float mean_s[NG * H];
    __shared__ float z_s[NG * H];
    __shared__ float cnt_s[NG];
    __shared__ float hid_s[NG * 64];
    int tid = threadIdx.x;
    if (tid < NG) cnt_s[tid] = fmaxf((float)pcnt[tid], 1.0f);
    __syncthreads();
    for (int i = tid; i < NG * H; i += 1024) {
        float s = 0.f;
        for (int p = 0; p < NPART; p++) s += poolpart[p * (NG * H) + i];
        mean_s[i] = s / cnt_s[i >> 7];
    }
    __syncthreads();
#pragma unroll
    for (int r = 0; r < 2; r++) {
        int i = tid + r * 1024;
        int g = i >> 7, j = i & (H - 1);
        float acc = b4[j];
        for (int f = 0; f < H; f++) acc += mean_s[g * H + f] * W4[f * H + j];
        z_s[i] = acc;
    }
    __syncthreads();
    {
        int g = tid >> 6, j = tid & 63;
        float acc = lb1[j];
        for (int f = 0; f < H; f++) acc += z_s[g * H + f] * lw1[f * 64 + j];
        hid_s[g * 64 + j] = fmaxf(acc, 0.f);
    }
    __syncthreads();
    if (tid < 32) {
        int g = tid >> 1, c = tid & 1;
        float acc = lb2[c];
        for (int j = 0; j < 64; j++) acc += hid_s[g * 64 + j] * lw2[j * 2 + c];
        out[g * 2 + c] = acc;
    }
}

extern "C" void kernel_launch(void* const* d_in, const int* in_sizes, int n_in,
                              void* d_out, int out_size, void* d_ws, size_t ws_size,
                              hipStream_t stream) {
    const float* x = (const float*)d_in[0];
    const int* ei = (const int*)d_in[1];
    const int* batch = (const int*)d_in[2];
    const float* W1 = (const float*)d_in[3];
    const float* b1 = (const float*)d_in[4];
    const float* W2 = (const float*)d_in[5];
    const float* b2 = (const float*)d_in[6];
    const float* W3 = (const float*)d_in[7];
    const float* b3 = (const float*)d_in[8];
    const float* W4 = (const float*)d_in[9];
    const float* b4 = (const float*)d_in[10];
    const float* lw1 = (const float*)d_in[11];
    const float* lb1 = (const float*)d_in[12];
    const float* lw2 = (const float*)d_in[13];
    const float* lb2 = (const float*)d_in[14];
    float* out = (float*)d_out;

    // workspace layout (4-byte units; sizes annotated in ints); ~39.5 MB
    int* wsi = (int*)d_ws;
    int* gcount = wsi;                                      // @0        256
    int* galloc = wsi + 256;                                // @256      1
    int* pcnt = wsi + 280;                                  // @280      16 (zeroed to 512)
    float* poolpart = (float*)(wsi + 512);                  // @512      131072 (NPART*NG*H)
    int2* rowse = (int2*)(wsi + 131584);                    // @131584   100096 (NPAD int2)
    unsigned short* csr = (unsigned short*)(wsi + 231680);  // @231680   600000 (1.2M ushorts)
    float* dinv = (float*)(wsi + 831680);                   // @831680   50048
    unsigned short* Wt1 = (unsigned short*)(wsi + 881728);  // @881728   4096 (8192 shorts)
    unsigned short* Wt2 = (unsigned short*)(wsi + 885824);  // @885824   8192 (16384 shorts)
    unsigned short* Wt3 = (unsigned short*)(wsi + 894016);  // @894016   8192
    unsigned short* xb = (unsigned short*)(wsi + 910400);   // @910400   1601536 (NPAD*64 shorts)
    unsigned int* hb = (unsigned int*)(wsi + 2511936);      // @2511936  3203072 (NPAD*64 uints)
    unsigned int* hwb = (unsigned int*)(wsi + 5715008);     // @5715008  3203072 (also holds xa)
    unsigned int* ebuf = (unsigned int*)(wsi + 8918080);    // @8918080  940800 -> ends 9858880

    const int gemmBlocks = NPAD / 64;          // 782
    const int aggxBlocks = NPAD / 32;          // 1564 (32 nodes/block, 64-dim rows)
    const int agg0Blocks = NPAD / 16;          // 3128 (16 nodes/block, 128-dim rows)
    const int poolBlocks = NPAD / 64;          // 782 (64 nodes/block, pooled)

    // ---- zero control vars (tiny); pool partials zeroed inside prep ----
    hipMemsetAsync(wsi, 0, 512 * sizeof(int), stream);
    fillA_prep_kernel<<<FILLA_BLOCKS + PREP_BLOCKS, 256, 0, stream>>>(
        ei, gcount, ebuf, W1, W2, W3, Wt1, Wt2, Wt3, (int4*)poolpart);
    fillB_kernel<<<NBUCK, 256, 0, stream>>>(ebuf, gcount, galloc, pcnt, batch, x,
                                            rowse, dinv, xb, csr);

    // ---- layer 1 agg: xa = agg(x-hat) (64-dim), lives in hwb ----
    aggx_kernel<<<aggxBlocks, 256, 0, stream>>>((const unsigned int*)xb, rowse, csr,
                                                dinv, hwb);
    // ---- layers 1+2 GEMMs fused (row-local): hb = (relu(xa@W1+b1) @ W2) * dinv ----
    gemm12_kernel<<<gemmBlocks, 256, 0, stream>>>((unsigned short*)hwb, Wt1, Wt2, b1,
                                                  dinv, hb);
    // ---- layer 2 agg: hwb = relu(agg(hb)*d + b2) (H2) ----
    agg_kernel<0><<<agg0Blocks, 256, 0, stream>>>(hb, rowse, csr, dinv, b2, batch,
                                                  nullptr, hwb);
    // ---- layer 3 GEMM: hb = (H2 @ W3) * dinv ----
    gemm_mfma_kernel<H><<<gemmBlocks, 256, 0, stream>>>((unsigned short*)hwb, Wt3,
                                                        dinv, hb);
    // ---- layer 3 agg (pre-scaled for layer-4): hwb = relu(agg(hb)*d + b3)*d ----
    agg_kernel<2><<<agg0Blocks, 256, 0, stream>>>(hb, rowse, csr, dinv, b3, batch,
                                                  nullptr, hwb);
    // ---- layer 4: aggregation + pooling directly on h3' (W4 folded into MLP) ----
    agg_kernel<1><<<poolBlocks, 256, 0, stream>>>(hwb, rowse, csr, dinv, nullptr, batch,
                                                  poolpart, nullptr);

    // ---- final MLP (applies W4, b4, then the classifier) ----
    mlp_kernel<<<1, 1024, 0, stream>>>(poolpart, pcnt, W4, b4, lw1, lb1, lw2, lb2, out);
}

// Round 13
// 287.808 us; speedup vs baseline: 1.0356x; 1.0031x over previous
//
#include <hip/hip_runtime.h>

#define NN 50000
#define NPAD 50048   // rows padded to multiple of 64 for MFMA tiles
#define NE 800000
#define FIN 64
#define H 128
#define NG 16
#define NPART 64         // private pooled-accumulator copies (atomic spreading)
#define NBUCK 196        // buckets of 256 dst nodes
#define BUCK_CAP 4800    // edges per bucket capacity (expected 4096 +- 64)
#define FILLA_BLOCKS 512
#define FILLA_CHUNK 1563  // ceil(NE / FILLA_BLOCKS)
#define ROW_U 64         // uints per node row (128 bf16 feats, 256 B)
#define XROW_U 32        // uints per x row (64 bf16 feats, 128 B)
#define DUMMY NN         // zero pad row used for CSR padding
#define ZERO_I4 32768    // int4s to zero: poolpart = 131072 ints
#define PREP_ITEMS (H * FIN + 2 * H * H + ZERO_I4)
#define PREP_BLOCKS ((PREP_ITEMS + 255) / 256)

typedef __bf16 bf16x8 __attribute__((ext_vector_type(8)));
typedef float f32x4 __attribute__((ext_vector_type(4)));
typedef float f32x2 __attribute__((ext_vector_type(2)));
typedef unsigned int u32x4 __attribute__((ext_vector_type(4)));

// ---- helpers ----
__device__ inline unsigned short bf16r(float x) {
    unsigned int u = __float_as_uint(x);
    return (unsigned short)((u + 0x7fffu + ((u >> 16) & 1u)) >> 16);
}
__device__ inline unsigned int pack_bf16x2(float a, float b) {
    return (unsigned int)bf16r(a) | ((unsigned int)bf16r(b) << 16);
}
__device__ inline float bf_lo(unsigned int u) { return __uint_as_float(u << 16); }
__device__ inline float bf_hi(unsigned int u) { return __uint_as_float(u & 0xffff0000u); }

// packed fp32 add: acc(pair) += {lo(u), hi(u)}
__device__ inline void pkadd(f32x2& a, unsigned int u) {
    f32x2 p;
    p.x = bf_lo(u);
    p.y = bf_hi(u);
    asm("v_pk_add_f32 %0, %1, %0" : "+v"(a) : "v"(p));
}
__device__ inline void bfly(f32x2& a, int m) {
    a.x += __shfl_xor(a.x, m);
    a.y += __shfl_xor(a.y, m);
}

// ====== fillA + prep merged: blocks [0,512) bucket edges; rest convert W + zero pool ======
__global__ __launch_bounds__(256) void fillA_prep_kernel(const int* __restrict__ ei,
                                                         int* __restrict__ gcount,
                                                         unsigned int* __restrict__ ebuf,
                                                         const float* __restrict__ W1,
                                                         const float* __restrict__ W2,
                                                         const float* __restrict__ W3,
                                                         unsigned short* __restrict__ Wt1,
                                                         unsigned short* __restrict__ Wt2,
                                                         unsigned short* __restrict__ Wt3,
                                                         int4* __restrict__ zbuf) {
    const int t = threadIdx.x;
    if (blockIdx.x >= FILLA_BLOCKS) {
        // ---- prep part ----
        int e = (blockIdx.x - FILLA_BLOCKS) * 256 + t;
        if (e < H * FIN) {
            int n = e / FIN, k = e % FIN;
            Wt1[e] = bf16r(W1[k * H + n]);
            return;
        }
        int u = e - H * FIN;
        if (u < 2 * H * H) {
            const float* W = W2;
            unsigned short* Wt = Wt2;
            if (u >= H * H) { W = W3; Wt = Wt3; u -= H * H; }
            int n = u / H, k = u % H;
            Wt[u] = bf16r(W[k * H + n]);
            return;
        }
        int z = u - 2 * H * H;
        if (z < ZERO_I4) zbuf[z] = make_int4(0, 0, 0, 0);  // zero pool partials
        return;
    }
    // ---- fillA part: histogram into 196 buckets of 256 nodes ----
    __shared__ int hist[256];
    __shared__ int base[256];
    hist[t] = 0;
    __syncthreads();
    const int e0 = blockIdx.x * FILLA_CHUNK;
    const int e1 = min(e0 + FILLA_CHUNK, NE);
    for (int e = e0 + t; e < e1; e += 256)
        atomicAdd(&hist[ei[NE + e] >> 8], 1);
    __syncthreads();
    {
        int h = hist[t];
        base[t] = h ? atomicAdd(&gcount[t], h) : 0;
    }
    __syncthreads();
    for (int e = e0 + t; e < e1; e += 256) {
        int d = ei[NE + e];
        int s = ei[e];
        int b = d >> 8;
        int pos = atomicAdd(&base[b], 1);
        ebuf[b * BUCK_CAP + pos] = (unsigned int)s | ((unsigned int)d << 16);
    }
}

// fillB (fused hist+scan+scatter), 196 blocks, 1 node per thread.
// Also: per-graph node counts (pcnt) and fused xprep (xb = bf16(x*dinv)).
__global__ __launch_bounds__(256) void fillB_kernel(const unsigned int* __restrict__ ebuf,
                                                    const int* __restrict__ gcount,
                                                    int* __restrict__ galloc,
                                                    int* __restrict__ pcnt,
                                                    const int* __restrict__ batch,
                                                    const float* __restrict__ x,
                                                    int2* __restrict__ rowse,
                                                    float* __restrict__ dinv,
                                                    unsigned short* __restrict__ xb,
                                                    unsigned short* __restrict__ csr) {
    __shared__ int lh[256];
    __shared__ int lsum[256];
    __shared__ int lcur[256];
    __shared__ int lgc[16];
    __shared__ int base_s;
    const int b = blockIdx.x, t = threadIdx.x;
    const int n0 = b * 256;
    lh[t] = 0;
    if (t < 16) lgc[t] = 0;
    __syncthreads();
    const int ne = gcount[b];
    const unsigned int* __restrict__ eb = ebuf + b * BUCK_CAP;
    for (int i = t; i < ne; i += 256)
        atomicAdd(&lh[(int)(eb[i] >> 16) - n0], 1);
    __syncthreads();
    const int c = lh[t];
    const int p = (c + 7) & ~7;
    const int n = n0 + t;
    if (n < NN) atomicAdd(&lgc[batch[n]], 1);
    lsum[t] = p;
    __syncthreads();
    if (t < 16 && lgc[t]) atomicAdd(&pcnt[t], lgc[t]);
    for (int off = 1; off < 256; off <<= 1) {
        int u = (t >= off) ? lsum[t - off] : 0;
        __syncthreads();
        lsum[t] += u;
        __syncthreads();
    }
    if (t == 255) base_s = atomicAdd(galloc, lsum[255]);
    const int excl = t ? lsum[t - 1] : 0;
    __syncthreads();
    const int st = base_s + excl;
    if (n < NN) {
        rowse[n] = make_int2(st, st + p);
        dinv[n] = rsqrtf((float)c + 1.0f);  // +1 self-loop
    } else if (n < NPAD) {
        rowse[n] = make_int2(0, 0);
        dinv[n] = 0.0f;
    }
    lcur[t] = st;
    __syncthreads();
    for (int i = t; i < ne; i += 256) {
        unsigned int u = eb[i];
        int pos = atomicAdd(&lcur[(int)(u >> 16) - n0], 1);
        csr[pos] = (unsigned short)(u & 0xFFFFu);
    }
    __syncthreads();
    for (int k = st + c; k < st + p; k++) csr[k] = (unsigned short)DUMMY;
    // ---- fused xprep: this block's 256 rows, xb = bf16(x * dinv); pads zero ----
    for (int i = t; i < 4096; i += 256) {  // 256 rows x 16 float4
        int nl = i >> 4;
        int nn = n0 + nl;
        if (nn >= NPAD) continue;
        uint2 o = make_uint2(0u, 0u);
        if (nn < NN) {
            float4 v = *(const float4*)&x[(size_t)nn * 64 + (i & 15) * 4];
            float d = rsqrtf((float)lh[nl] + 1.0f);
            o.x = pack_bf16x2(v.x * d, v.y * d);
            o.y = pack_bf16x2(v.z * d, v.w * d);
        }
        *(uint2*)&xb[(size_t)nn * 64 + (i & 15) * 4] = o;
    }
}

#define LSTRIDE 130

// ===== gemm12 fused (row-local): hw2' = (relu(xa@W1 + b1) @ W2) * dinv =====
// H1 never touches global memory; bf16 rounding of H1 identical to the unfused path.
__global__ __launch_bounds__(256) void gemm12_kernel(const unsigned short* __restrict__ xa,
                                                     const unsigned short* __restrict__ Wt1,
                                                     const unsigned short* __restrict__ Wt2,
                                                     const float* __restrict__ b1,
                                                     const float* __restrict__ dinv,
                                                     unsigned int* __restrict__ outu) {
    __shared__ float ls[64 * LSTRIDE];  // ~33 KB
    const int wave = threadIdx.x >> 6, lane = threadIdx.x & 63;
    const int m15 = lane & 15, quad = lane >> 4;
    const int row0 = blockIdx.x * 64;
    const int arow = row0 + wave * 16 + m15;
    const int lrow = wave * 16 + quad * 4;

    // --- stage 1: H1 tile = relu(xa @ W1 + b1) -> LDS (f32) ---
    bf16x8 a[2];
#pragma unroll
    for (int ks = 0; ks < 2; ks++)
        a[ks] = *(const bf16x8*)&xa[(size_t)arow * FIN + ks * 32 + quad * 8];

#pragma unroll
    for (int ct = 0; ct < 8; ct++) {
        f32x4 acc = {0.f, 0.f, 0.f, 0.f};
#pragma unroll
        for (int ks = 0; ks < 2; ks++) {
            bf16x8 bfr = *(const bf16x8*)&Wt1[(ct * 16 + m15) * FIN + ks * 32 + quad * 8];
            acc = __builtin_amdgcn_mfma_f32_16x16x32_bf16(a[ks], bfr, acc, 0, 0, 0);
        }
        float bv = b1[ct * 16 + m15];
#pragma unroll
        for (int r = 0; r < 4; r++)
            ls[(lrow + r) * LSTRIDE + ct * 16 + m15] = fmaxf(acc[r] + bv, 0.f);
    }
    __syncthreads();

    // --- stage 2: read own A-fragments of H1, round to bf16 (same as old store path) ---
    bf16x8 h[4];
#pragma unroll
    for (int ks = 0; ks < 4; ks++) {
        const float* p = &ls[(wave * 16 + m15) * LSTRIDE + ks * 32 + quad * 8];
        u32x4 pk;
        pk[0] = pack_bf16x2(p[0], p[1]);
        pk[1] = pack_bf16x2(p[2], p[3]);
        pk[2] = pack_bf16x2(p[4], p[5]);
        pk[3] = pack_bf16x2(p[6], p[7]);
        h[ks] = *(bf16x8*)&pk;
    }
    __syncthreads();  // all lanes finished reading ls before overwrite

    float dv[4];
#pragma unroll
    for (int r = 0; r < 4; r++) dv[r] = dinv[row0 + lrow + r];

    // --- stage 3: hw2' = (H1 @ W2) * dinv -> LDS -> bf16 NT store ---
#pragma unroll
    for (int ct = 0; ct < 8; ct++) {
        f32x4 acc = {0.f, 0.f, 0.f, 0.f};
#pragma unroll
        for (int ks = 0; ks < 4; ks++) {
            bf16x8 bfr = *(const bf16x8*)&Wt2[(ct * 16 + m15) * H + ks * 32 + quad * 8];
            acc = __builtin_amdgcn_mfma_f32_16x16x32_bf16(h[ks], bfr, acc, 0, 0, 0);
        }
#pragma unroll
        for (int r = 0; r < 4; r++)
            ls[(lrow + r) * LSTRIDE + ct * 16 + m15] = acc[r] * dv[r];
    }
    __syncthreads();

#pragma unroll
    for (int k = 0; k < 4; k++) {
        int idx = threadIdx.x + 256 * k;
        int row = idx >> 4, q = idx & 15;
        const float* p = &ls[row * LSTRIDE + q * 8];
        u32x4 o;
        o[0] = pack_bf16x2(p[0], p[1]);
        o[1] = pack_bf16x2(p[2], p[3]);
        o[2] = pack_bf16x2(p[4], p[5]);
        o[3] = pack_bf16x2(p[6], p[7]);
        __builtin_nontemporal_store(
            o, (u32x4*)&outu[(size_t)(row0 + row) * ROW_U + q * 4]);
    }
}

// ===== MFMA GEMM (gemm3): row-major in/out, epilogue *dinv[row] =====
template <int K>
__global__ __launch_bounds__(256) void gemm_mfma_kernel(const unsigned short* __restrict__ hb,
                                                        const unsigned short* __restrict__ Wt,
                                                        const float* __restrict__ dinv,
                                                        unsigned int* __restrict__ outu) {
    __shared__ float ls[64 * LSTRIDE];  // ~33 KB
    const int wave = threadIdx.x >> 6, lane = threadIdx.x & 63;
    const int m15 = lane & 15, quad = lane >> 4;
    const int row0 = blockIdx.x * 64;
    const int arow = row0 + wave * 16 + m15;

    bf16x8 a[K / 32];
#pragma unroll
    for (int ks = 0; ks < K / 32; ks++)
        a[ks] = *(const bf16x8*)&hb[(size_t)arow * K + ks * 32 + quad * 8];

    const int lrow = wave * 16 + quad * 4;
    float dv[4];
#pragma unroll
    for (int r = 0; r < 4; r++) dv[r] = dinv[row0 + lrow + r];

#pragma unroll
    for (int ct = 0; ct < 8; ct++) {
        f32x4 acc = {0.f, 0.f, 0.f, 0.f};
#pragma unroll
        for (int ks = 0; ks < K / 32; ks++) {
            bf16x8 b = *(const bf16x8*)&Wt[(ct * 16 + m15) * K + ks * 32 + quad * 8];
            acc = __builtin_amdgcn_mfma_f32_16x16x32_bf16(a[ks], b, acc, 0, 0, 0);
        }
#pragma unroll
        for (int r = 0; r < 4; r++)
            ls[(lrow + r) * LSTRIDE + ct * 16 + m15] = acc[r] * dv[r];
    }
    __syncthreads();

#pragma unroll
    for (int k = 0; k < 4; k++) {
        int idx = threadIdx.x + 256 * k;
        int row = idx >> 4, q = idx & 15;
        const float* p = &ls[row * LSTRIDE + q * 8];
        u32x4 o;
        o[0] = pack_bf16x2(p[0], p[1]);
        o[1] = pack_bf16x2(p[2], p[3]);
        o[2] = pack_bf16x2(p[4], p[5]);
        o[3] = pack_bf16x2(p[6], p[7]);
        __builtin_nontemporal_store(
            o, (u32x4*)&outu[(size_t)(row0 + row) * ROW_U + q * 4]);
    }
}

// ---- gather one node's aggregated row slice (16 B/lane; RU uints per row) ----
template <int RU>
__device__ inline void gather_row(const unsigned int* __restrict__ hwc,
                                  const int2* __restrict__ rowse,
                                  const unsigned short* __restrict__ csr,
                                  int n, int u0,
                                  f32x2& a0, f32x2& a1, f32x2& a2, f32x2& a3) {
    uint4 sv = *(const uint4*)&hwc[(size_t)n * RU + u0];  // self-loop term
    a0.x = bf_lo(sv.x); a0.y = bf_hi(sv.x);
    a1.x = bf_lo(sv.y); a1.y = bf_hi(sv.y);
    a2.x = bf_lo(sv.z); a2.y = bf_hi(sv.z);
    a3.x = bf_lo(sv.w); a3.y = bf_hi(sv.w);
    const int2 se = rowse[n];  // start/end, both multiples of 8
    int i = se.x;
    for (; i + 16 <= se.y; i += 16) {  // unroll x2: 16 gathers outstanding
        u32x4 c0 = __builtin_nontemporal_load((const u32x4*)&csr[i]);
        u32x4 c1 = __builtin_nontemporal_load((const u32x4*)&csr[i + 8]);
        int s0 = c0[0] & 0xFFFF, s1 = c0[0] >> 16;
        int s2 = c0[1] & 0xFFFF, s3 = c0[1] >> 16;
        int s4 = c0[2] & 0xFFFF, s5 = c0[2] >> 16;
        int s6 = c0[3] & 0xFFFF, s7 = c0[3] >> 16;
        int t0 = c1[0] & 0xFFFF, t1 = c1[0] >> 16;
        int t2 = c1[1] & 0xFFFF, t3 = c1[1] >> 16;
        int t4 = c1[2] & 0xFFFF, t5 = c1[2] >> 16;
        int t6 = c1[3] & 0xFFFF, t7 = c1[3] >> 16;
        uint4 v0 = *(const uint4*)&hwc[(size_t)s0 * RU + u0];
        uint4 v1 = *(const uint4*)&hwc[(size_t)s1 * RU + u0];
        uint4 v2 = *(const uint4*)&hwc[(size_t)s2 * RU + u0];
        uint4 v3 = *(const uint4*)&hwc[(size_t)s3 * RU + u0];
        uint4 v4 = *(const uint4*)&hwc[(size_t)s4 * RU + u0];
        uint4 v5 = *(const uint4*)&hwc[(size_t)s5 * RU + u0];
        uint4 v6 = *(const uint4*)&hwc[(size_t)s6 * RU + u0];
        uint4 v7 = *(const uint4*)&hwc[(size_t)s7 * RU + u0];
        uint4 w0 = *(const uint4*)&hwc[(size_t)t0 * RU + u0];
        uint4 w1 = *(const uint4*)&hwc[(size_t)t1 * RU + u0];
        uint4 w2 = *(const uint4*)&hwc[(size_t)t2 * RU + u0];
        uint4 w3 = *(const uint4*)&hwc[(size_t)t3 * RU + u0];
        uint4 w4 = *(const uint4*)&hwc[(size_t)t4 * RU + u0];
        uint4 w5 = *(const uint4*)&hwc[(size_t)t5 * RU + u0];
        uint4 w6 = *(const uint4*)&hwc[(size_t)t6 * RU + u0];
        uint4 w7 = *(const uint4*)&hwc[(size_t)t7 * RU + u0];
        pkadd(a0, v0.x); pkadd(a1, v0.y); pkadd(a2, v0.z); pkadd(a3, v0.w);
        pkadd(a0, v1.x); pkadd(a1, v1.y); pkadd(a2, v1.z); pkadd(a3, v1.w);
        pkadd(a0, v2.x); pkadd(a1, v2.y); pkadd(a2, v2.z); pkadd(a3, v2.w);
        pkadd(a0, v3.x); pkadd(a1, v3.y); pkadd(a2, v3.z); pkadd(a3, v3.w);
        pkadd(a0, v4.x); pkadd(a1, v4.y); pkadd(a2, v4.z); pkadd(a3, v4.w);
        pkadd(a0, v5.x); pkadd(a1, v5.y); pkadd(a2, v5.z); pkadd(a3, v5.w);
        pkadd(a0, v6.x); pkadd(a1, v6.y); pkadd(a2, v6.z); pkadd(a3, v6.w);
        pkadd(a0, v7.x); pkadd(a1, v7.y); pkadd(a2, v7.z); pkadd(a3, v7.w);
        pkadd(a0, w0.x); pkadd(a1, w0.y); pkadd(a2, w0.z); pkadd(a3, w0.w);
        pkadd(a0, w1.x); pkadd(a1, w1.y); pkadd(a2, w1.z); pkadd(a3, w1.w);
        pkadd(a0, w2.x); pkadd(a1, w2.y); pkadd(a2, w2.z); pkadd(a3, w2.w);
        pkadd(a0, w3.x); pkadd(a1, w3.y); pkadd(a2, w3.z); pkadd(a3, w3.w);
        pkadd(a0, w4.x); pkadd(a1, w4.y); pkadd(a2, w4.z); pkadd(a3, w4.w);
        pkadd(a0, w5.x); pkadd(a1, w5.y); pkadd(a2, w5.z); pkadd(a3, w5.w);
        pkadd(a0, w6.x); pkadd(a1, w6.y); pkadd(a2, w6.z); pkadd(a3, w6.w);
        pkadd(a0, w7.x); pkadd(a1, w7.y); pkadd(a2, w7.z); pkadd(a3, w7.w);
    }
    if (i < se.y) {  // remainder is exactly one 8-group
        u32x4 c = __builtin_nontemporal_load((const u32x4*)&csr[i]);
        int s0 = c[0] & 0xFFFF, s1 = c[0] >> 16;
        int s2 = c[1] & 0xFFFF, s3 = c[1] >> 16;
        int s4 = c[2] & 0xFFFF, s5 = c[2] >> 16;
        int s6 = c[3] & 0xFFFF, s7 = c[3] >> 16;
        uint4 v0 = *(const uint4*)&hwc[(size_t)s0 * RU + u0];
        uint4 v1 = *(const uint4*)&hwc[(size_t)s1 * RU + u0];
        uint4 v2 = *(const uint4*)&hwc[(size_t)s2 * RU + u0];
        uint4 v3 = *(const uint4*)&hwc[(size_t)s3 * RU + u0];
        uint4 v4 = *(const uint4*)&hwc[(size_t)s4 * RU + u0];
        uint4 v5 = *(const uint4*)&hwc[(size_t)s5 * RU + u0];
        uint4 v6 = *(const uint4*)&hwc[(size_t)s6 * RU + u0];
        uint4 v7 = *(const uint4*)&hwc[(size_t)s7 * RU + u0];
        pkadd(a0, v0.x); pkadd(a1, v0.y); pkadd(a2, v0.z); pkadd(a3, v0.w);
        pkadd(a0, v1.x); pkadd(a1, v1.y); pkadd(a2, v1.z); pkadd(a3, v1.w);
        pkadd(a0, v2.x); pkadd(a1, v2.y); pkadd(a2, v2.z); pkadd(a3, v2.w);
        pkadd(a0, v3.x); pkadd(a1, v3.y); pkadd(a2, v3.z); pkadd(a3, v3.w);
        pkadd(a0, v4.x); pkadd(a1, v4.y); pkadd(a2, v4.z); pkadd(a3, v4.w);
        pkadd(a0, v5.x); pkadd(a1, v5.y); pkadd(a2, v5.z); pkadd(a3, v5.w);
        pkadd(a0, v6.x); pkadd(a1, v6.y); pkadd(a2, v6.z); pkadd(a3, v6.w);
        pkadd(a0, v7.x); pkadd(a1, v7.y); pkadd(a2, v7.z); pkadd(a3, v7.w);
    }
}

// ====== agg_x: layer-1 pre-aggregation on 64-dim x-hat rows (1 transaction/edge) ======
// 8 lanes/node, 32 nodes/block. out = (self + sum) * dinv[n], bf16.
__global__ __launch_bounds__(256) void aggx_kernel(const unsigned int* __restrict__ xbu,
                                                   const int2* __restrict__ rowse,
                                                   const unsigned short* __restrict__ csr,
                                                   const float* __restrict__ dinv,
                                                   unsigned int* __restrict__ xa) {
    const int u0 = (threadIdx.x & 7) * 4;
    const int n = blockIdx.x * 32 + (threadIdx.x >> 3);
    f32x2 a0, a1, a2, a3;
    gather_row<XROW_U>(xbu, rowse, csr, n, u0, a0, a1, a2, a3);
    const float d = dinv[n];
    u32x4 o;
    o[0] = pack_bf16x2(a0.x * d, a0.y * d);
    o[1] = pack_bf16x2(a1.x * d, a1.y * d);
    o[2] = pack_bf16x2(a2.x * d, a2.y * d);
    o[3] = pack_bf16x2(a3.x * d, a3.y * d);
    __builtin_nontemporal_store(o, (u32x4*)&xa[(size_t)n * XROW_U + u0]);
}

// ====== full-row gather aggregation (128-dim): 16 lanes/node, 16 nodes/block ======
// MODE 0: relu(a*d + bias) -> bf16 (agg2).  MODE 2: relu(a*d + bias)*d (agg3, pre-scaled
// for layer-4 gather).  MODE 1: pooled (layer 4, no gemm): single gather pass, *d,
// wave butterfly + LDS cross-wave combine -> 128 atomics/block (load-balanced 3128 grid;
// round-9 lesson: gathers want max blocks + min serial phases).
template <int MODE>
__global__ __launch_bounds__(256) void agg_kernel(const unsigned int* __restrict__ hwc,
                                                  const int2* __restrict__ rowse,
                                                  const unsigned short* __restrict__ csr,
                                                  const float* __restrict__ dinv,
                                                  const float* __restrict__ bias,
                                                  const int* __restrict__ batch,
                                                  float* __restrict__ poolpart,
                                                  unsigned int* __restrict__ outc) {
    const int u = threadIdx.x & 15;
    const int u0 = u * 4;
    const int n = blockIdx.x * 16 + (threadIdx.x >> 4);
    if (MODE != 1) {
        f32x2 a0, a1, a2, a3;
        gather_row<ROW_U>(hwc, rowse, csr, n, u0, a0, a1, a2, a3);
        const float d = dinv[n];
        const float2* bp = (const float2*)bias + u0;
        float2 q0 = bp[0], q1 = bp[1], q2 = bp[2], q3 = bp[3];
        float r0 = fmaxf(a0.x * d + q0.x, 0.f), r1 = fmaxf(a0.y * d + q0.y, 0.f);
        float r2 = fmaxf(a1.x * d + q1.x, 0.f), r3 = fmaxf(a1.y * d + q1.y, 0.f);
        float r4 = fmaxf(a2.x * d + q2.x, 0.f), r5 = fmaxf(a2.y * d + q2.y, 0.f);
        float r6 = fmaxf(a3.x * d + q3.x, 0.f), r7 = fmaxf(a3.y * d + q3.y, 0.f);
        if (MODE == 2) {  // pre-scale for the gemm-free layer-4 gather
            r0 *= d; r1 *= d; r2 *= d; r3 *= d;
            r4 *= d; r5 *= d; r6 *= d; r7 *= d;
        }
        u32x4 o;
        o[0] = pack_bf16x2(r0, r1);
        o[1] = pack_bf16x2(r2, r3);
        o[2] = pack_bf16x2(r4, r5);
        o[3] = pack_bf16x2(r6, r7);
        __builtin_nontemporal_store(o, (u32x4*)&outc[(size_t)n * ROW_U + u0]);
        return;
    }
    // ---- MODE 1: layer-4 aggregation + pooling (single gather pass per thread) ----
    __shared__ float lds[4][128];
    const int lane = threadIdx.x & 63, wave = threadIdx.x >> 6;
    const int n0 = blockIdx.x * 16;
    const int copy = blockIdx.x & (NPART - 1);
    const int gfirst0 = batch[min(n0, NN - 1)];
    const bool blockUni = (gfirst0 == batch[min(n0 + 15, NN - 1)]);
    float* __restrict__ ppb = poolpart + copy * (NG * H);

    f32x2 t0, t1, t2, t3;
    gather_row<ROW_U>(hwc, rowse, csr, n, u0, t0, t1, t2, t3);
    const float d = dinv[n];  // 0 for pad rows -> they vanish
    t0 *= d; t1 *= d; t2 *= d; t3 *= d;

    if (blockUni) {
        // butterfly over the wave's 4 nodes -> lanes 0-15 hold the wave sum
        bfly(t0, 16); bfly(t1, 16); bfly(t2, 16); bfly(t3, 16);
        bfly(t0, 32); bfly(t1, 32); bfly(t2, 32); bfly(t3, 32);
        if (lane < 16) {
            float* q = &lds[wave][lane * 8];
            q[0] = t0.x; q[1] = t0.y;
            q[2] = t1.x; q[3] = t1.y;
            q[4] = t2.x; q[5] = t2.y;
            q[6] = t3.x; q[7] = t3.y;
        }
        __syncthreads();
        if (threadIdx.x < 128) {
            float tot = lds[0][threadIdx.x] + lds[1][threadIdx.x] +
                        lds[2][threadIdx.x] + lds[3][threadIdx.x];
            atomicAdd(&ppb[gfirst0 * H + threadIdx.x], tot);
        }
        return;
    }
    // rare graph-boundary block (<=15 of 3128): per-wave handling
    const int gb = batch[min(n, NN - 1)];
    const bool uni = (__shfl(gb, 0) == __shfl(gb, 63));
    if (uni) {
        bfly(t0, 16); bfly(t1, 16); bfly(t2, 16); bfly(t3, 16);
        bfly(t0, 32); bfly(t1, 32); bfly(t2, 32); bfly(t3, 32);
        if (lane < 16) {
            float* q = ppb + __shfl(gb, 0) * H + lane * 8;
            atomicAdd(&q[0], t0.x); atomicAdd(&q[1], t0.y);
            atomicAdd(&q[2], t1.x); atomicAdd(&q[3], t1.y);
            atomicAdd(&q[4], t2.x); atomicAdd(&q[5], t2.y);
            atomicAdd(&q[6], t3.x); atomicAdd(&q[7], t3.y);
        }
    } else if (n < NN) {
        float* q = ppb + gb * H + u * 8;
        atomicAdd(&q[0], t0.x); atomicAdd(&q[1], t0.y);
        atomicAdd(&q[2], t1.x); atomicAdd(&q[3], t1.y);
        atomicAdd(&q[4], t2.x); atomicAdd(&q[5], t2.y);
        atomicAdd(&q[6], t3.x); atomicAdd(&q[7], t3.y);
    }
}

// ===== final MLP: reduce NPART copies -> mean -> @W4+b4 -> @lw1 relu -> @lw2 =====
__global__ __launch_bounds__(1024) void mlp_kernel(const float* __restrict__ poolpart,
                                                   const int* __restrict__ pcnt,
                                                   const float* __restrict__ W4,
                                                   const float* __restrict__ b4,
                                                   const float* __restrict__ lw1,
                                                   const float* __restrict__ lb1,
                                                   const float* __restrict__ lw2,
                                                   const float* __restrict__ lb2,
                                                   float* __restrict__ out) {
    __shared__ float mean_s[NG * H];
    __shared__ float z_s[NG * H];
    __shared__ float cnt_s[NG];
    __shared__ float hid_s[NG * 64];
    int tid = threadIdx.x;
    if (tid < NG) cnt_s[tid] = fmaxf((float)pcnt[tid], 1.0f);
    __syncthreads();
    for (int i = tid; i < NG * H; i += 1024) {
        float s = 0.f;
        for (int p = 0; p < NPART; p++) s += poolpart[p * (NG * H) + i];
        mean_s[i] = s / cnt_s[i >> 7];
    }
    __syncthreads();
#pragma unroll
    for (int r = 0; r < 2; r++) {
        int i = tid + r * 1024;
        int g = i >> 7, j = i & (H - 1);
        float acc = b4[j];
        for (int f = 0; f < H; f++) acc += mean_s[g * H + f] * W4[f * H + j];
        z_s[i] = acc;
    }
    __syncthreads();
    {
        int g = tid >> 6, j = tid & 63;
        float acc = lb1[j];
        for (int f = 0; f < H; f++) acc += z_s[g * H + f] * lw1[f * 64 + j];
        hid_s[g * 64 + j] = fmaxf(acc, 0.f);
    }
    __syncthreads();
    if (tid < 32) {
        int g = tid >> 1, c = tid & 1;
        float acc = lb2[c];
        for (int j = 0; j < 64; j++) acc += hid_s[g * 64 + j] * lw2[j * 2 + c];
        out[g * 2 + c] = acc;
    }
}

extern "C" void kernel_launch(void* const* d_in, const int* in_sizes, int n_in,
                              void* d_out, int out_size, void* d_ws, size_t ws_size,
                              hipStream_t stream) {
    const float* x = (const float*)d_in[0];
    const int* ei = (const int*)d_in[1];
    const int* batch = (const int*)d_in[2];
    const float* W1 = (const float*)d_in[3];
    const float* b1 = (const float*)d_in[4];
    const float* W2 = (const float*)d_in[5];
    const float* b2 = (const float*)d_in[6];
    const float* W3 = (const float*)d_in[7];
    const float* b3 = (const float*)d_in[8];
    const float* W4 = (const float*)d_in[9];
    const float* b4 = (const float*)d_in[10];
    const float* lw1 = (const float*)d_in[11];
    const float* lb1 = (const float*)d_in[12];
    const float* lw2 = (const float*)d_in[13];
    const float* lb2 = (const float*)d_in[14];
    float* out = (float*)d_out;

    // workspace layout (4-byte units; sizes annotated in ints); ~39.5 MB
    int* wsi = (int*)d_ws;
    int* gcount = wsi;                                      // @0        256
    int* galloc = wsi + 256;                                // @256      1
    int* pcnt = wsi + 280;                                  // @280      16 (zeroed to 512)
    float* poolpart = (float*)(wsi + 512);                  // @512      131072 (NPART*NG*H)
    int2* rowse = (int2*)(wsi + 131584);                    // @131584   100096 (NPAD int2)
    unsigned short* csr = (unsigned short*)(wsi + 231680);  // @231680   600000 (1.2M ushorts)
    float* dinv = (float*)(wsi + 831680);                   // @831680   50048
    unsigned short* Wt1 = (unsigned short*)(wsi + 881728);  // @881728   4096 (8192 shorts)
    unsigned short* Wt2 = (unsigned short*)(wsi + 885824);  // @885824   8192 (16384 shorts)
    unsigned short* Wt3 = (unsigned short*)(wsi + 894016);  // @894016   8192
    unsigned short* xb = (unsigned short*)(wsi + 910400);   // @910400   1601536 (NPAD*64 shorts)
    unsigned int* hb = (unsigned int*)(wsi + 2511936);      // @2511936  3203072 (NPAD*64 uints)
    unsigned int* hwb = (unsigned int*)(wsi + 5715008);     // @5715008  3203072 (also holds xa)
    unsigned int* ebuf = (unsigned int*)(wsi + 8918080);    // @8918080  940800 -> ends 9858880

    const int gemmBlocks = NPAD / 64;          // 782
    const int aggxBlocks = NPAD / 32;          // 1564 (32 nodes/block, 64-dim rows)
    const int agg0Blocks = NPAD / 16;          // 3128 (16 nodes/block, 128-dim rows)

    // ---- zero control vars (tiny); pool partials zeroed inside prep ----
    hipMemsetAsync(wsi, 0, 512 * sizeof(int), stream);
    fillA_prep_kernel<<<FILLA_BLOCKS + PREP_BLOCKS, 256, 0, stream>>>(
        ei, gcount, ebuf, W1, W2, W3, Wt1, Wt2, Wt3, (int4*)poolpart);
    fillB_kernel<<<NBUCK, 256, 0, stream>>>(ebuf, gcount, galloc, pcnt, batch, x,
                                            rowse, dinv, xb, csr);

    // ---- layer 1 agg: xa = agg(x-hat) (64-dim), lives in hwb ----
    aggx_kernel<<<aggxBlocks, 256, 0, stream>>>((const unsigned int*)xb, rowse, csr,
                                                dinv, hwb);
    // ---- layers 1+2 GEMMs fused (row-local): hb = (relu(xa@W1+b1) @ W2) * dinv ----
    gemm12_kernel<<<gemmBlocks, 256, 0, stream>>>((unsigned short*)hwb, Wt1, Wt2, b1,
                                                  dinv, hb);
    // ---- layer 2 agg: hwb = relu(agg(hb)*d + b2) (H2) ----
    agg_kernel<0><<<agg0Blocks, 256, 0, stream>>>(hb, rowse, csr, dinv, b2, batch,
                                                  nullptr, hwb);
    // ---- layer 3 GEMM: hb = (H2 @ W3) * dinv ----
    gemm_mfma_kernel<H><<<gemmBlocks, 256, 0, stream>>>((unsigned short*)hwb, Wt3,
                                                        dinv, hb);
    // ---- layer 3 agg (pre-scaled for layer-4): hwb = relu(agg(hb)*d + b3)*d ----
    agg_kernel<2><<<agg0Blocks, 256, 0, stream>>>(hb, rowse, csr, dinv, b3, batch,
                                                  nullptr, hwb);
    // ---- layer 4: aggregation + pooling directly on h3' (W4 folded into MLP) ----
    agg_kernel<1><<<agg0Blocks, 256, 0, stream>>>(hwb, rowse, csr, dinv, nullptr, batch,
                                                  poolpart, nullptr);

    // ---- final MLP (applies W4, b4, then the classifier) ----
    mlp_kernel<<<1, 1024, 0, stream>>>(poolpart, pcnt, W4, b4, lw1, lb1, lw2, lb2, out);
}